// Round 13
// baseline (321.583 us; speedup 1.0000x reference)
//
#include <hip/hip_runtime.h>

constexpr int N = 50000;
constexpr int E = 800000;
constexpr int D = 128;
constexpr int MASKN = 25000;
constexpr int CAP = 64; // bucket = exactly two 64B lines; deg~Poisson(16), 12 sigma
constexpr int HB = 128;           // histogram blocks
constexpr int HW = (N + 1) / 2;   // packed 2x16-bit words

typedef _Float16 half8 __attribute__((ext_vector_type(8)));
typedef _Float16 half4 __attribute__((ext_vector_type(4)));
typedef _Float16 half2v __attribute__((ext_vector_type(2)));
typedef float f32x4 __attribute__((ext_vector_type(4)));

#define ROW8(X) X(0) X(1) X(2) X(3) X(4) X(5) X(6) X(7)

// ---------------- bucket build: cursor atomic + scatter only ----------------

__global__ void k_build(const int* __restrict__ src, const int* __restrict__ dst,
                        int* __restrict__ cursor, unsigned short* __restrict__ col) {
    int e = blockIdx.x * blockDim.x + threadIdx.x;
    if (e < E) {
        int s = src[e], d = dst[e];
        int p = atomicAdd(&cursor[d], 1);
        col[(size_t)d * CAP + p] = (unsigned short)s;
    }
}

// ---------------- out-degree histogram: LDS-privatized, packed 2x16-bit ------

__launch_bounds__(256)
__global__ void k_hist(const int* __restrict__ src, unsigned int* __restrict__ partial) {
    __shared__ unsigned int hcnt[HW];
    int b = blockIdx.x, t = threadIdx.x;
    for (int i = t; i < HW; i += 256) hcnt[i] = 0u;
    __syncthreads();
    constexpr int PER = E / HB; // 6250
    int base = b * PER;
    for (int i = t; i < PER; i += 256) {
        int s = src[base + i];
        atomicAdd(&hcnt[s >> 1], 1u << ((s & 1) * 16));
    }
    __syncthreads();
    unsigned int* outp = partial + (size_t)b * HW;
    for (int i = t; i < HW; i += 256) outp[i] = hcnt[i];
}

// ---------------- fused setup: 4x W->fp16 cast + dinv (partial-sum) + mflag --

__global__ void k_misc(const float* __restrict__ W1, const float* __restrict__ W2,
                       const float* __restrict__ WE, const float* __restrict__ WD,
                       _Float16* __restrict__ Wh1, _Float16* __restrict__ Wh2,
                       _Float16* __restrict__ WhE, _Float16* __restrict__ WhD,
                       const unsigned int* __restrict__ partial,
                       const int* __restrict__ cd,
                       float* __restrict__ dinv_out, float* __restrict__ dinv_in,
                       const int* __restrict__ mask_nodes, int* __restrict__ mflag) {
    int b = blockIdx.x, t = threadIdx.x;
    if (b < 16) { // 4 matrices x 4 blocks, 4096 elems each
        int m = b >> 2;
        const float* W = m == 0 ? W1 : m == 1 ? W2 : m == 2 ? WE : WD;
        _Float16* Wh = m == 0 ? Wh1 : m == 1 ? Wh2 : m == 2 ? WhE : WhD;
        int base = (b & 3) * 4096 + t;
#pragma unroll
        for (int j = 0; j < 16; ++j) Wh[base + j * 256] = (_Float16)W[base + j * 256];
    } else if (b < 16 + 196) {
        int i = (b - 16) * 256 + t;
        if (i < N) {
            int word = i >> 1, sh = (i & 1) * 16;
            unsigned int sum = 0;
#pragma unroll 8
            for (int bb = 0; bb < HB; ++bb)
                sum += (partial[(size_t)bb * HW + word] >> sh) & 0xffffu;
            int a = sum > 1u ? (int)sum : 1;
            int bb2 = cd[i] > 1 ? cd[i] : 1;
            dinv_out[i] = rsqrtf((float)a);
            dinv_in[i] = rsqrtf((float)bb2);
        }
    } else {
        int i = (b - 212) * 256 + t;
        if (i < MASKN) mflag[mask_nodes[i]] = 1;
    }
}

// ---------------- feature prep: masked x scaled by deg_out^-0.5, fp16 out ----

__global__ void k_prep(const float4* __restrict__ x, const float4* __restrict__ tok,
                       const int* __restrict__ mflag, const float* __restrict__ dinv_out,
                       half4* __restrict__ Ah4) {
    int i = blockIdx.x * blockDim.x + threadIdx.x; // over N*32 float4s
    if (i < N * 32) {
        int row = i >> 5;
        int c = i & 31;
        float s = dinv_out[row];
        float4 v = mflag[row] ? tok[c] : x[i];
        half4 h;
        h[0] = (_Float16)(v.x * s);
        h[1] = (_Float16)(v.y * s);
        h[2] = (_Float16)(v.z * s);
        h[3] = (_Float16)(v.w * s);
        Ah4[i] = h;
    }
}

// ---------------- shared device helpers ----------------
// gather one row's neighbor sum into registers (quarter-wave per edge)

__device__ __forceinline__ void gather_row(const half8* __restrict__ Ah8,
                                           const int* __restrict__ deg,
                                           const unsigned short* __restrict__ col,
                                           int row, int q, int j,
                                           float& a0, float& a1, float& a2, float& a3,
                                           float& a4, float& a5, float& a6, float& a7) {
    int dg = deg[row];
    const unsigned short* crow = col + (size_t)row * CAP;
    int e = q;
    for (; e + 12 < dg; e += 16) {
        int c0 = crow[e], c1 = crow[e + 4], c2 = crow[e + 8], c3 = crow[e + 12];
        half8 h0 = Ah8[(size_t)c0 * 16 + j];
        half8 h1 = Ah8[(size_t)c1 * 16 + j];
        half8 h2 = Ah8[(size_t)c2 * 16 + j];
        half8 h3 = Ah8[(size_t)c3 * 16 + j];
#define SP_ACC4(i) a##i += (float)h0[i]; a##i += (float)h1[i];                 \
                   a##i += (float)h2[i]; a##i += (float)h3[i];
        ROW8(SP_ACC4)
#undef SP_ACC4
    }
    for (; e + 4 < dg; e += 8) {
        int c0 = crow[e], c1 = crow[e + 4];
        half8 h0 = Ah8[(size_t)c0 * 16 + j];
        half8 h1 = Ah8[(size_t)c1 * 16 + j];
#define SP_ACC(i) a##i += (float)h0[i]; a##i += (float)h1[i];
        ROW8(SP_ACC)
#undef SP_ACC
    }
    if (e < dg) {
        int c0 = crow[e];
        half8 h0 = Ah8[(size_t)c0 * 16 + j];
#define SP_ACC1(i) a##i += (float)h0[i];
        ROW8(SP_ACC1)
#undef SP_ACC1
    }
}

// ---------------- fused SpMM + MFMA fc + LN/PReLU epilogue -------------------
// phase 1: gather 32 rows' aggregates -> fp16 LDS (each wave 8 rows);
// phase 2: MFMA vs Wh (verified layout R10); LN + epilogue -> outh.

template <bool LN, bool SCALE_OUT, bool MASK_ZERO>
__launch_bounds__(256)
__global__ void k_spmf(const half8* __restrict__ Ah8, _Float16* __restrict__ outh,
                       const _Float16* __restrict__ Wh,
                       const float* __restrict__ bias, const float* __restrict__ g,
                       const float* __restrict__ be, const float* __restrict__ aP,
                       const float* __restrict__ dinv_in, const float* __restrict__ dinv_out,
                       const int* __restrict__ mflag,
                       const int* __restrict__ deg, const unsigned short* __restrict__ col) {
    __shared__ _Float16 shh[32][136];
    __shared__ float shc[32][132];
    __shared__ float smu[32], srs[32];
    int t = threadIdx.x;
    int w = t >> 6, lane = t & 63;
    int rl = lane & 15, quad = lane >> 4;
    int q = quad, j = rl;
    int r0 = blockIdx.x * 32;
    // phase 1: gather
    for (int rr = 0; rr < 8; ++rr) {
        int lr = w * 8 + rr;
        int row = r0 + lr;
        float a0 = 0.f, a1 = 0.f, a2 = 0.f, a3 = 0.f;
        float a4 = 0.f, a5 = 0.f, a6 = 0.f, a7 = 0.f;
        if (row < N) gather_row(Ah8, deg, col, row, q, j, a0, a1, a2, a3, a4, a5, a6, a7);
#pragma unroll
        for (int o = 16; o <= 32; o <<= 1) {
#define SP_SHFL(i) a##i += __shfl_xor(a##i, o);
            ROW8(SP_SHFL)
#undef SP_SHFL
        }
        if (q == 0) {
            half8 ho;
#define SP_PACK(i) ho[i] = (_Float16)a##i;
            ROW8(SP_PACK)
#undef SP_PACK
            *(half8*)&shh[lr][j * 8] = ho;
        }
    }
    __syncthreads();
    // phase 2: MFMA
    const half8* B0p = (const half8*)(Wh + (size_t)(w * 32 + rl) * 128 + quad * 8);
    const half8* B1p = (const half8*)(Wh + (size_t)(w * 32 + 16 + rl) * 128 + quad * 8);
    f32x4 c00 = {0.f, 0.f, 0.f, 0.f}, c01 = c00, c10 = c00, c11 = c00;
#pragma unroll
    for (int kk = 0; kk < 4; ++kk) {
        half8 a0 = *(const half8*)&shh[rl][kk * 32 + quad * 8];
        half8 a1 = *(const half8*)&shh[16 + rl][kk * 32 + quad * 8];
        half8 b0 = B0p[kk * 4];
        half8 b1 = B1p[kk * 4];
        c00 = __builtin_amdgcn_mfma_f32_16x16x32_f16(a0, b0, c00, 0, 0, 0);
        c01 = __builtin_amdgcn_mfma_f32_16x16x32_f16(a0, b1, c01, 0, 0, 0);
        c10 = __builtin_amdgcn_mfma_f32_16x16x32_f16(a1, b0, c10, 0, 0, 0);
        c11 = __builtin_amdgcn_mfma_f32_16x16x32_f16(a1, b1, c11, 0, 0, 0);
    }
#pragma unroll
    for (int reg = 0; reg < 4; ++reg) {
        shc[quad * 4 + reg][w * 32 + rl] = c00[reg];
        shc[quad * 4 + reg][w * 32 + 16 + rl] = c01[reg];
        shc[16 + quad * 4 + reg][w * 32 + rl] = c10[reg];
        shc[16 + quad * 4 + reg][w * 32 + 16 + rl] = c11[reg];
    }
    __syncthreads();
    if constexpr (LN) {
        int row = t >> 3, seg = t & 7;
        int rr = r0 + row;
        float di = dinv_in[rr > N - 1 ? N - 1 : rr];
        float s = 0.f, qq = 0.f;
#pragma unroll
        for (int c = 0; c < 16; ++c) {
            int cc = seg * 16 + c;
            float v = (shc[row][cc] + bias[cc]) * di;
            s += v;
            qq += v * v;
        }
#pragma unroll
        for (int o = 1; o <= 4; o <<= 1) {
            s += __shfl_xor(s, o);
            qq += __shfl_xor(qq, o);
        }
        if (seg == 0) {
            float mu = s * (1.f / 128.f);
            float var = qq * (1.f / 128.f) - mu * mu;
            smu[row] = mu;
            srs[row] = rsqrtf(var + 1e-5f);
        }
        __syncthreads();
    }
    int lane64 = t & 63, grp = t >> 6;
    int cc0 = lane64 * 2, cc1 = cc0 + 1;
    float bt0 = 0.f, bt1 = 0.f, gt0 = 0.f, gt1 = 0.f, be0 = 0.f, be1 = 0.f, alpha = 0.f;
    if constexpr (LN) {
        bt0 = bias[cc0]; bt1 = bias[cc1];
        gt0 = g[cc0]; gt1 = g[cc1];
        be0 = be[cc0]; be1 = be[cc1];
        alpha = aP[0];
    }
#pragma unroll
    for (int i = 0; i < 8; ++i) {
        int lr = grp * 8 + i, r = r0 + lr;
        if (r < N) {
            float v0 = shc[lr][cc0], v1 = shc[lr][cc1];
            if constexpr (LN) {
                float di = dinv_in[r];
                v0 = (v0 + bt0) * di;
                v1 = (v1 + bt1) * di;
                float mu = smu[lr], rs = srs[lr];
                v0 = (v0 - mu) * rs * gt0 + be0;
                v1 = (v1 - mu) * rs * gt1 + be1;
                v0 = v0 >= 0.f ? v0 : alpha * v0;
                v1 = v1 >= 0.f ? v1 : alpha * v1;
            }
            if (MASK_ZERO && mflag[r]) { v0 = 0.f; v1 = 0.f; }
            if constexpr (SCALE_OUT) {
                float so = dinv_out[r];
                v0 *= so; v1 *= so;
            }
            half2v hv;
            hv[0] = (_Float16)v0;
            hv[1] = (_Float16)v1;
            *(half2v*)(outh + (size_t)r * 128 + cc0) = hv;
        }
    }
}

// ---------------- fused SpMM + conv2-fc/LN + encoder_to_decoder (MFMA x2) ----

__launch_bounds__(256)
__global__ void k_spmf2(const half8* __restrict__ Ah8, _Float16* __restrict__ outh,
                        const _Float16* __restrict__ Wh2, const _Float16* __restrict__ WhE,
                        const float* __restrict__ bias, const float* __restrict__ g,
                        const float* __restrict__ be, const float* __restrict__ aP,
                        const float* __restrict__ dinv_in, const float* __restrict__ dinv_out,
                        const int* __restrict__ mflag,
                        const int* __restrict__ deg, const unsigned short* __restrict__ col) {
    __shared__ _Float16 shh[32][136];
    __shared__ float shc[32][132];
    __shared__ float smu[32], srs[32], sdo[32];
    __shared__ int smf[32];
    int t = threadIdx.x;
    int w = t >> 6, lane = t & 63;
    int rl = lane & 15, quad = lane >> 4;
    int q = quad, j = rl;
    int r0 = blockIdx.x * 32;
    if (t < 32) {
        int r = r0 + t;
        int rc = r > N - 1 ? N - 1 : r;
        sdo[t] = dinv_out[rc];
        smf[t] = mflag[rc];
    }
    // phase 1: gather agg2 -> shh
    for (int rr = 0; rr < 8; ++rr) {
        int lr = w * 8 + rr;
        int row = r0 + lr;
        float a0 = 0.f, a1 = 0.f, a2 = 0.f, a3 = 0.f;
        float a4 = 0.f, a5 = 0.f, a6 = 0.f, a7 = 0.f;
        if (row < N) gather_row(Ah8, deg, col, row, q, j, a0, a1, a2, a3, a4, a5, a6, a7);
#pragma unroll
        for (int o = 16; o <= 32; o <<= 1) {
#define SP_SHFL(i) a##i += __shfl_xor(a##i, o);
            ROW8(SP_SHFL)
#undef SP_SHFL
        }
        if (q == 0) {
            half8 ho;
#define SP_PACK(i) ho[i] = (_Float16)a##i;
            ROW8(SP_PACK)
#undef SP_PACK
            *(half8*)&shh[lr][j * 8] = ho;
        }
    }
    __syncthreads();
    // phase 2a: MFMA vs Wh2
    const half8* B0p = (const half8*)(Wh2 + (size_t)(w * 32 + rl) * 128 + quad * 8);
    const half8* B1p = (const half8*)(Wh2 + (size_t)(w * 32 + 16 + rl) * 128 + quad * 8);
    f32x4 c00 = {0.f, 0.f, 0.f, 0.f}, c01 = c00, c10 = c00, c11 = c00;
#pragma unroll
    for (int kk = 0; kk < 4; ++kk) {
        half8 a0 = *(const half8*)&shh[rl][kk * 32 + quad * 8];
        half8 a1 = *(const half8*)&shh[16 + rl][kk * 32 + quad * 8];
        half8 b0 = B0p[kk * 4];
        half8 b1 = B1p[kk * 4];
        c00 = __builtin_amdgcn_mfma_f32_16x16x32_f16(a0, b0, c00, 0, 0, 0);
        c01 = __builtin_amdgcn_mfma_f32_16x16x32_f16(a0, b1, c01, 0, 0, 0);
        c10 = __builtin_amdgcn_mfma_f32_16x16x32_f16(a1, b0, c10, 0, 0, 0);
        c11 = __builtin_amdgcn_mfma_f32_16x16x32_f16(a1, b1, c11, 0, 0, 0);
    }
#pragma unroll
    for (int reg = 0; reg < 4; ++reg) {
        shc[quad * 4 + reg][w * 32 + rl] = c00[reg];
        shc[quad * 4 + reg][w * 32 + 16 + rl] = c01[reg];
        shc[16 + quad * 4 + reg][w * 32 + rl] = c10[reg];
        shc[16 + quad * 4 + reg][w * 32 + 16 + rl] = c11[reg];
    }
    __syncthreads();
    { // LN stats
        int row = t >> 3, seg = t & 7;
        int rr = r0 + row;
        float di = dinv_in[rr > N - 1 ? N - 1 : rr];
        float s = 0.f, qq = 0.f;
#pragma unroll
        for (int c = 0; c < 16; ++c) {
            int cc = seg * 16 + c;
            float v = (shc[row][cc] + bias[cc]) * di;
            s += v;
            qq += v * v;
        }
#pragma unroll
        for (int o = 1; o <= 4; o <<= 1) {
            s += __shfl_xor(s, o);
            qq += __shfl_xor(qq, o);
        }
        if (seg == 0) {
            float mu = s * (1.f / 128.f);
            float var = qq * (1.f / 128.f) - mu * mu;
            smu[row] = mu;
            srs[row] = rsqrtf(var + 1e-5f);
        }
        __syncthreads();
    }
    { // h2 -> shh (fp16) [safe: all shh reads completed before prior barrier]
        int lane64 = t & 63, grp = t >> 6;
        int cc0 = lane64 * 2, cc1 = cc0 + 1;
        float bt0 = bias[cc0], bt1 = bias[cc1];
        float gt0 = g[cc0], gt1 = g[cc1];
        float be0 = be[cc0], be1 = be[cc1];
        float alpha = aP[0];
#pragma unroll
        for (int i = 0; i < 8; ++i) {
            int lr = grp * 8 + i, r = r0 + lr;
            float v0 = 0.f, v1 = 0.f;
            if (r < N) {
                float di = dinv_in[r];
                v0 = (shc[lr][cc0] + bt0) * di;
                v1 = (shc[lr][cc1] + bt1) * di;
                float mu = smu[lr], rs = srs[lr];
                v0 = (v0 - mu) * rs * gt0 + be0;
                v1 = (v1 - mu) * rs * gt1 + be1;
                v0 = v0 >= 0.f ? v0 : alpha * v0;
                v1 = v1 >= 0.f ? v1 : alpha * v1;
            }
            shh[lr][cc0] = (_Float16)v0;
            shh[lr][cc1] = (_Float16)v1;
        }
    }
    __syncthreads();
    // phase 2b: rep = h2 @ We2d, register-direct epilogue
    const half8* E0p = (const half8*)(WhE + (size_t)(w * 32 + rl) * 128 + quad * 8);
    const half8* E1p = (const half8*)(WhE + (size_t)(w * 32 + 16 + rl) * 128 + quad * 8);
    f32x4 d00 = {0.f, 0.f, 0.f, 0.f}, d01 = d00, d10 = d00, d11 = d00;
#pragma unroll
    for (int kk = 0; kk < 4; ++kk) {
        half8 a0 = *(const half8*)&shh[rl][kk * 32 + quad * 8];
        half8 a1 = *(const half8*)&shh[16 + rl][kk * 32 + quad * 8];
        half8 b0 = E0p[kk * 4];
        half8 b1 = E1p[kk * 4];
        d00 = __builtin_amdgcn_mfma_f32_16x16x32_f16(a0, b0, d00, 0, 0, 0);
        d01 = __builtin_amdgcn_mfma_f32_16x16x32_f16(a0, b1, d01, 0, 0, 0);
        d10 = __builtin_amdgcn_mfma_f32_16x16x32_f16(a1, b0, d10, 0, 0, 0);
        d11 = __builtin_amdgcn_mfma_f32_16x16x32_f16(a1, b1, d11, 0, 0, 0);
    }
#pragma unroll
    for (int reg = 0; reg < 4; ++reg) {
        int lr = quad * 4 + reg, r = r0 + lr;
        if (r < N) {
            float s = smf[lr] ? 0.f : sdo[lr];
            outh[(size_t)r * 128 + w * 32 + rl] = (_Float16)(d00[reg] * s);
            outh[(size_t)r * 128 + w * 32 + 16 + rl] = (_Float16)(d01[reg] * s);
        }
        int lr2 = 16 + lr, r2 = r0 + lr2;
        if (r2 < N) {
            float s = smf[lr2] ? 0.f : sdo[lr2];
            outh[(size_t)r2 * 128 + w * 32 + rl] = (_Float16)(d10[reg] * s);
            outh[(size_t)r2 * 128 + w * 32 + 16 + rl] = (_Float16)(d11[reg] * s);
        }
    }
}

// ---------------- fused conv3-SpMM + decoder fc + SCE loss -------------------

__launch_bounds__(256)
__global__ void k_spmf_loss(const half8* __restrict__ Ah8, const float* __restrict__ x,
                            const _Float16* __restrict__ Wh, const float* __restrict__ bd,
                            const int* __restrict__ deg, const unsigned short* __restrict__ col,
                            const float* __restrict__ dinv_in,
                            const int* __restrict__ mask_nodes, float* __restrict__ outp) {
    __shared__ float shc[32][132];
    __shared__ _Float16 shh[32][136];
    __shared__ int shm[32];
    __shared__ float sterm[32];
    int t = threadIdx.x;
    int w = t >> 6, lane = t & 63;
    int rl = lane & 15, quad = lane >> 4;
    int q = quad, j = rl;
    int i0 = blockIdx.x * 32;
    if (t < 32) {
        int idx = i0 + t;
        shm[t] = idx < MASKN ? mask_nodes[idx] : -1;
    }
    __syncthreads();
    for (int rr = 0; rr < 8; ++rr) {
        int lr = w * 8 + rr;
        int m = shm[lr];
        float a0 = 0.f, a1 = 0.f, a2 = 0.f, a3 = 0.f;
        float a4 = 0.f, a5 = 0.f, a6 = 0.f, a7 = 0.f;
        if (m >= 0) gather_row(Ah8, deg, col, m, q, j, a0, a1, a2, a3, a4, a5, a6, a7);
#pragma unroll
        for (int o = 16; o <= 32; o <<= 1) {
#define SP_SHFL(i) a##i += __shfl_xor(a##i, o);
            ROW8(SP_SHFL)
#undef SP_SHFL
        }
        if (q == 0) {
            half8 ho;
#define SP_PACK(i) ho[i] = (_Float16)a##i;
            ROW8(SP_PACK)
#undef SP_PACK
            *(half8*)&shh[lr][j * 8] = ho;
        }
    }
    __syncthreads();
    const half8* B0p = (const half8*)(Wh + (size_t)(w * 32 + rl) * 128 + quad * 8);
    const half8* B1p = (const half8*)(Wh + (size_t)(w * 32 + 16 + rl) * 128 + quad * 8);
    f32x4 c00 = {0.f, 0.f, 0.f, 0.f}, c01 = c00, c10 = c00, c11 = c00;
#pragma unroll
    for (int kk = 0; kk < 4; ++kk) {
        half8 a0 = *(const half8*)&shh[rl][kk * 32 + quad * 8];
        half8 a1 = *(const half8*)&shh[16 + rl][kk * 32 + quad * 8];
        half8 b0 = B0p[kk * 4];
        half8 b1 = B1p[kk * 4];
        c00 = __builtin_amdgcn_mfma_f32_16x16x32_f16(a0, b0, c00, 0, 0, 0);
        c01 = __builtin_amdgcn_mfma_f32_16x16x32_f16(a0, b1, c01, 0, 0, 0);
        c10 = __builtin_amdgcn_mfma_f32_16x16x32_f16(a1, b0, c10, 0, 0, 0);
        c11 = __builtin_amdgcn_mfma_f32_16x16x32_f16(a1, b1, c11, 0, 0, 0);
    }
#pragma unroll
    for (int reg = 0; reg < 4; ++reg) {
        shc[quad * 4 + reg][w * 32 + rl] = c00[reg];
        shc[quad * 4 + reg][w * 32 + 16 + rl] = c01[reg];
        shc[16 + quad * 4 + reg][w * 32 + rl] = c10[reg];
        shc[16 + quad * 4 + reg][w * 32 + 16 + rl] = c11[reg];
    }
    __syncthreads();
    int row = t >> 3, seg = t & 7;
    int m = shm[row];
    float a = 0.f, b = 0.f, c = 0.f;
    if (m >= 0) {
        float di = dinv_in[m];
#pragma unroll
        for (int cc0 = 0; cc0 < 16; ++cc0) {
            int cc = seg * 16 + cc0;
            float r = (shc[row][cc] + bd[cc]) * di;
            float xv = x[(size_t)m * 128 + cc];
            a += r * r;
            b += xv * xv;
            c += r * xv;
        }
    }
#pragma unroll
    for (int o = 1; o <= 4; o <<= 1) {
        a += __shfl_xor(a, o);
        b += __shfl_xor(b, o);
        c += __shfl_xor(c, o);
    }
    if (seg == 0) {
        float term = 0.f;
        if (m >= 0) {
            float nr = fmaxf(sqrtf(a), 1e-12f);
            float nx = fmaxf(sqrtf(b), 1e-12f);
            float d = 1.f - c / (nr * nx);
            term = d * d;
        }
        sterm[row] = term;
    }
    __syncthreads();
    if (t == 0) {
        float sum = 0.f;
#pragma unroll
        for (int i = 0; i < 32; ++i) sum += sterm[i];
        atomicAdd(outp, sum * (1.f / MASKN));
    }
}

// ---------------- launch ----------------

extern "C" void kernel_launch(void* const* d_in, const int* in_sizes, int n_in,
                              void* d_out, int out_size, void* d_ws, size_t ws_size,
                              hipStream_t stream) {
    const float* x = (const float*)d_in[0];
    const float* tok = (const float*)d_in[1];
    const float* W1 = (const float*)d_in[2];
    const float* b1 = (const float*)d_in[3];
    const float* g1 = (const float*)d_in[4];
    const float* be1 = (const float*)d_in[5];
    const float* a1 = (const float*)d_in[6];
    const float* W2 = (const float*)d_in[7];
    const float* b2 = (const float*)d_in[8];
    const float* g2 = (const float*)d_in[9];
    const float* be2 = (const float*)d_in[10];
    const float* a2 = (const float*)d_in[11];
    const float* We2d = (const float*)d_in[12];
    const float* Wd = (const float*)d_in[13];
    const float* bd = (const float*)d_in[14];
    const int* src = (const int*)d_in[15];
    const int* dst = (const int*)d_in[16];
    const int* mask_nodes = (const int*)d_in[17];

    char* w = (char*)d_ws;
    _Float16* Ah = (_Float16*)w;        w += (size_t)N * D * 2;
    _Float16* Bh = (_Float16*)w;        w += (size_t)N * D * 2;
    unsigned short* col = (unsigned short*)w; w += (size_t)N * CAP * 2;
    int* cursor = (int*)w;              w += (size_t)N * 4; // becomes deg_in
    int* mflag = (int*)w;               w += (size_t)N * 4;
    float* dinv_out = (float*)w;        w += (size_t)N * 4;
    float* dinv_in = (float*)w;         w += (size_t)N * 4;
    _Float16* Wh1 = (_Float16*)w;       w += (size_t)D * D * 2;
    _Float16* Wh2 = (_Float16*)w;       w += (size_t)D * D * 2;
    _Float16* WhE = (_Float16*)w;       w += (size_t)D * D * 2;
    _Float16* WhD = (_Float16*)w;       w += (size_t)D * D * 2;
    unsigned int* partial = (unsigned int*)w; w += (size_t)HB * HW * 4;

    // zero cursor, mflag (contiguous 2*N ints) + output scalar
    hipMemsetAsync(cursor, 0, (size_t)2 * N * 4, stream);
    hipMemsetAsync(d_out, 0, sizeof(float), stream);

    k_build<<<(E + 255) / 256, 256, 0, stream>>>(src, dst, cursor, col);
    k_hist<<<HB, 256, 0, stream>>>(src, partial);
    k_misc<<<310, 256, 0, stream>>>(W1, W2, We2d, Wd, Wh1, Wh2, WhE, WhD,
                                    partial, cursor, dinv_out, dinv_in, mask_nodes, mflag);
    k_prep<<<(N * 32 + 255) / 256, 256, 0, stream>>>((const float4*)x, (const float4*)tok,
                                                     mflag, dinv_out, (half4*)Ah);
    int nmf = (N + 31) / 32;        // 1563
    int nmfl = (MASKN + 31) / 32;   // 782
    // conv1: agg + fc + LN + PReLU + pre-scale (fused) : Ah -> Bh
    k_spmf<true, true, false><<<nmf, 256, 0, stream>>>(
        (const half8*)Ah, Bh, Wh1, b1, g1, be1, a1, dinv_in, dinv_out, nullptr,
        cursor, col);
    // conv2: agg + fc/LN/PReLU + encoder_to_decoder + re-mask + pre-scale : Bh -> Ah
    k_spmf2<<<nmf, 256, 0, stream>>>(
        (const half8*)Bh, Ah, Wh2, WhE, b2, g2, be2, a2, dinv_in, dinv_out, mflag,
        cursor, col);
    // conv3 agg + decoder fc + SCE loss (fused)
    k_spmf_loss<<<nmfl, 256, 0, stream>>>((const half8*)Ah, x, WhD, bd, cursor, col,
                                          dinv_in, mask_nodes, (float*)d_out);
}

// Round 14
// 317.503 us; speedup vs baseline: 1.0129x; 1.0129x over previous
//
#include <hip/hip_runtime.h>

constexpr int N = 50000;
constexpr int E = 800000;
constexpr int D = 128;
constexpr int MASKN = 25000;
constexpr int CAP = 64; // bucket = exactly two 64B lines; deg~Poisson(16), 12 sigma
constexpr int HB = 128;           // histogram blocks
constexpr int HW = (N + 1) / 2;   // packed 2x16-bit words

typedef _Float16 half8 __attribute__((ext_vector_type(8)));
typedef _Float16 half4 __attribute__((ext_vector_type(4)));
typedef _Float16 half2v __attribute__((ext_vector_type(2)));
typedef float f32x4 __attribute__((ext_vector_type(4)));

#define ROW8(X) X(0) X(1) X(2) X(3) X(4) X(5) X(6) X(7)

// ---------------- bucket build: cursor atomic + scatter only ----------------

__global__ void k_build(const int* __restrict__ src, const int* __restrict__ dst,
                        int* __restrict__ cursor, unsigned short* __restrict__ col) {
    int e = blockIdx.x * blockDim.x + threadIdx.x;
    if (e < E) {
        int s = src[e], d = dst[e];
        int p = atomicAdd(&cursor[d], 1);
        col[(size_t)d * CAP + p] = (unsigned short)s;
    }
}

// ---------------- out-degree histogram: LDS-privatized, packed 2x16-bit ------

__launch_bounds__(256)
__global__ void k_hist(const int* __restrict__ src, unsigned int* __restrict__ partial) {
    __shared__ unsigned int hcnt[HW];
    int b = blockIdx.x, t = threadIdx.x;
    for (int i = t; i < HW; i += 256) hcnt[i] = 0u;
    __syncthreads();
    constexpr int PER = E / HB; // 6250
    int base = b * PER;
    for (int i = t; i < PER; i += 256) {
        int s = src[base + i];
        atomicAdd(&hcnt[s >> 1], 1u << ((s & 1) * 16));
    }
    __syncthreads();
    unsigned int* outp = partial + (size_t)b * HW;
    for (int i = t; i < HW; i += 256) outp[i] = hcnt[i];
}

// ---------------- fused setup: 4x W->fp16 cast + dinv (partial-sum) + mflag --

__global__ void k_misc(const float* __restrict__ W1, const float* __restrict__ W2,
                       const float* __restrict__ WE, const float* __restrict__ WD,
                       _Float16* __restrict__ Wh1, _Float16* __restrict__ Wh2,
                       _Float16* __restrict__ WhE, _Float16* __restrict__ WhD,
                       const unsigned int* __restrict__ partial,
                       const int* __restrict__ cd,
                       float* __restrict__ dinv_out, float* __restrict__ dinv_in,
                       const int* __restrict__ mask_nodes, int* __restrict__ mflag) {
    int b = blockIdx.x, t = threadIdx.x;
    if (b < 16) { // 4 matrices x 4 blocks, 4096 elems each
        int m = b >> 2;
        const float* W = m == 0 ? W1 : m == 1 ? W2 : m == 2 ? WE : WD;
        _Float16* Wh = m == 0 ? Wh1 : m == 1 ? Wh2 : m == 2 ? WhE : WhD;
        int base = (b & 3) * 4096 + t;
#pragma unroll
        for (int j = 0; j < 16; ++j) Wh[base + j * 256] = (_Float16)W[base + j * 256];
    } else if (b < 16 + 196) {
        int i = (b - 16) * 256 + t;
        if (i < N) {
            int word = i >> 1, sh = (i & 1) * 16;
            unsigned int sum = 0;
#pragma unroll 8
            for (int bb = 0; bb < HB; ++bb)
                sum += (partial[(size_t)bb * HW + word] >> sh) & 0xffffu;
            int a = sum > 1u ? (int)sum : 1;
            int bb2 = cd[i] > 1 ? cd[i] : 1;
            dinv_out[i] = rsqrtf((float)a);
            dinv_in[i] = rsqrtf((float)bb2);
        }
    } else {
        int i = (b - 212) * 256 + t;
        if (i < MASKN) mflag[mask_nodes[i]] = 1;
    }
}

// ---------------- feature prep: masked x scaled by deg_out^-0.5, fp16 out ----

__global__ void k_prep(const float4* __restrict__ x, const float4* __restrict__ tok,
                       const int* __restrict__ mflag, const float* __restrict__ dinv_out,
                       half4* __restrict__ Ah4) {
    int i = blockIdx.x * blockDim.x + threadIdx.x; // over N*32 float4s
    if (i < N * 32) {
        int row = i >> 5;
        int c = i & 31;
        float s = dinv_out[row];
        float4 v = mflag[row] ? tok[c] : x[i];
        half4 h;
        h[0] = (_Float16)(v.x * s);
        h[1] = (_Float16)(v.y * s);
        h[2] = (_Float16)(v.z * s);
        h[3] = (_Float16)(v.w * s);
        Ah4[i] = h;
    }
}

// ---------------- shared device helpers ----------------

__device__ __forceinline__ void gather_row(const half8* __restrict__ Ah8,
                                           const int* __restrict__ deg,
                                           const unsigned short* __restrict__ col,
                                           int row, int q, int j,
                                           float& a0, float& a1, float& a2, float& a3,
                                           float& a4, float& a5, float& a6, float& a7) {
    int dg = deg[row];
    const unsigned short* crow = col + (size_t)row * CAP;
    int e = q;
    for (; e + 12 < dg; e += 16) {
        int c0 = crow[e], c1 = crow[e + 4], c2 = crow[e + 8], c3 = crow[e + 12];
        half8 h0 = Ah8[(size_t)c0 * 16 + j];
        half8 h1 = Ah8[(size_t)c1 * 16 + j];
        half8 h2 = Ah8[(size_t)c2 * 16 + j];
        half8 h3 = Ah8[(size_t)c3 * 16 + j];
#define SP_ACC4(i) a##i += (float)h0[i]; a##i += (float)h1[i];                 \
                   a##i += (float)h2[i]; a##i += (float)h3[i];
        ROW8(SP_ACC4)
#undef SP_ACC4
    }
    for (; e + 4 < dg; e += 8) {
        int c0 = crow[e], c1 = crow[e + 4];
        half8 h0 = Ah8[(size_t)c0 * 16 + j];
        half8 h1 = Ah8[(size_t)c1 * 16 + j];
#define SP_ACC(i) a##i += (float)h0[i]; a##i += (float)h1[i];
        ROW8(SP_ACC)
#undef SP_ACC
    }
    if (e < dg) {
        int c0 = crow[e];
        half8 h0 = Ah8[(size_t)c0 * 16 + j];
#define SP_ACC1(i) a##i += (float)h0[i];
        ROW8(SP_ACC1)
#undef SP_ACC1
    }
}

// gather 4 rows per wave into shh (16-row tile, 4 waves)
#define GATHER16(ROWEXPR)                                                      \
    for (int rr = 0; rr < 4; ++rr) {                                           \
        int lr = w * 4 + rr;                                                   \
        int row = ROWEXPR;                                                     \
        float a0 = 0.f, a1 = 0.f, a2 = 0.f, a3 = 0.f;                          \
        float a4 = 0.f, a5 = 0.f, a6 = 0.f, a7 = 0.f;                          \
        if (row >= 0)                                                          \
            gather_row(Ah8, deg, col, row, quad, rl, a0, a1, a2, a3, a4, a5,   \
                       a6, a7);                                                \
        _Pragma("unroll") for (int o = 16; o <= 32; o <<= 1) {                 \
            a0 += __shfl_xor(a0, o); a1 += __shfl_xor(a1, o);                  \
            a2 += __shfl_xor(a2, o); a3 += __shfl_xor(a3, o);                  \
            a4 += __shfl_xor(a4, o); a5 += __shfl_xor(a5, o);                  \
            a6 += __shfl_xor(a6, o); a7 += __shfl_xor(a7, o);                  \
        }                                                                      \
        if (quad == 0) {                                                       \
            half8 ho;                                                          \
            ho[0] = (_Float16)a0; ho[1] = (_Float16)a1;                        \
            ho[2] = (_Float16)a2; ho[3] = (_Float16)a3;                        \
            ho[4] = (_Float16)a4; ho[5] = (_Float16)a5;                        \
            ho[6] = (_Float16)a6; ho[7] = (_Float16)a7;                        \
            *(half8*)&shh[lr][rl * 8] = ho;                                    \
        }                                                                      \
    }

// ---------------- fused SpMM + MFMA fc + LN/PReLU epilogue (16-row tile) -----

template <bool LN, bool SCALE_OUT, bool MASK_ZERO>
__launch_bounds__(256)
__global__ void k_spmf(const half8* __restrict__ Ah8, _Float16* __restrict__ outh,
                       const _Float16* __restrict__ Wh,
                       const float* __restrict__ bias, const float* __restrict__ g,
                       const float* __restrict__ be, const float* __restrict__ aP,
                       const float* __restrict__ dinv_in, const float* __restrict__ dinv_out,
                       const int* __restrict__ mflag,
                       const int* __restrict__ deg, const unsigned short* __restrict__ col) {
    __shared__ _Float16 shh[16][136];
    __shared__ float shc[16][132];
    __shared__ float smu[16], srs[16];
    int t = threadIdx.x;
    int w = t >> 6, lane = t & 63;
    int rl = lane & 15, quad = lane >> 4;
    int r0 = blockIdx.x * 16; // N % 16 == 0
    GATHER16(r0 + lr)
    __syncthreads();
    // MFMA: one A-fragment holds all 16 rows
    const half8* B0p = (const half8*)(Wh + (size_t)(w * 32 + rl) * 128 + quad * 8);
    const half8* B1p = (const half8*)(Wh + (size_t)(w * 32 + 16 + rl) * 128 + quad * 8);
    f32x4 c00 = {0.f, 0.f, 0.f, 0.f}, c01 = c00;
#pragma unroll
    for (int kk = 0; kk < 4; ++kk) {
        half8 a0 = *(const half8*)&shh[rl][kk * 32 + quad * 8];
        half8 b0 = B0p[kk * 4];
        half8 b1 = B1p[kk * 4];
        c00 = __builtin_amdgcn_mfma_f32_16x16x32_f16(a0, b0, c00, 0, 0, 0);
        c01 = __builtin_amdgcn_mfma_f32_16x16x32_f16(a0, b1, c01, 0, 0, 0);
    }
#pragma unroll
    for (int reg = 0; reg < 4; ++reg) {
        shc[quad * 4 + reg][w * 32 + rl] = c00[reg];
        shc[quad * 4 + reg][w * 32 + 16 + rl] = c01[reg];
    }
    __syncthreads();
    if constexpr (LN) {
        int row = t >> 4, seg = t & 15; // 16 threads/row, 8 cols each
        float di = dinv_in[r0 + row];
        float s = 0.f, qq = 0.f;
#pragma unroll
        for (int c = 0; c < 8; ++c) {
            int cc = seg * 8 + c;
            float v = (shc[row][cc] + bias[cc]) * di;
            s += v;
            qq += v * v;
        }
#pragma unroll
        for (int o = 1; o <= 8; o <<= 1) {
            s += __shfl_xor(s, o);
            qq += __shfl_xor(qq, o);
        }
        if (seg == 0) {
            float mu = s * (1.f / 128.f);
            float var = qq * (1.f / 128.f) - mu * mu;
            smu[row] = mu;
            srs[row] = rsqrtf(var + 1e-5f);
        }
        __syncthreads();
    }
    int lane64 = t & 63, grp = t >> 6;
    int cc0 = lane64 * 2, cc1 = cc0 + 1;
    float bt0 = 0.f, bt1 = 0.f, gt0 = 0.f, gt1 = 0.f, be0 = 0.f, be1 = 0.f, alpha = 0.f;
    if constexpr (LN) {
        bt0 = bias[cc0]; bt1 = bias[cc1];
        gt0 = g[cc0]; gt1 = g[cc1];
        be0 = be[cc0]; be1 = be[cc1];
        alpha = aP[0];
    }
#pragma unroll
    for (int i = 0; i < 4; ++i) {
        int lr = grp * 4 + i, r = r0 + lr;
        float v0 = shc[lr][cc0], v1 = shc[lr][cc1];
        if constexpr (LN) {
            float di = dinv_in[r];
            v0 = (v0 + bt0) * di;
            v1 = (v1 + bt1) * di;
            float mu = smu[lr], rs = srs[lr];
            v0 = (v0 - mu) * rs * gt0 + be0;
            v1 = (v1 - mu) * rs * gt1 + be1;
            v0 = v0 >= 0.f ? v0 : alpha * v0;
            v1 = v1 >= 0.f ? v1 : alpha * v1;
        }
        if (MASK_ZERO && mflag[r]) { v0 = 0.f; v1 = 0.f; }
        if constexpr (SCALE_OUT) {
            float so = dinv_out[r];
            v0 *= so; v1 *= so;
        }
        half2v hv;
        hv[0] = (_Float16)v0;
        hv[1] = (_Float16)v1;
        *(half2v*)(outh + (size_t)r * 128 + cc0) = hv;
    }
}

// ---------------- fused SpMM + conv2-fc/LN + encoder_to_decoder (16-row) -----

__launch_bounds__(256)
__global__ void k_spmf2(const half8* __restrict__ Ah8, _Float16* __restrict__ outh,
                        const _Float16* __restrict__ Wh2, const _Float16* __restrict__ WhE,
                        const float* __restrict__ bias, const float* __restrict__ g,
                        const float* __restrict__ be, const float* __restrict__ aP,
                        const float* __restrict__ dinv_in, const float* __restrict__ dinv_out,
                        const int* __restrict__ mflag,
                        const int* __restrict__ deg, const unsigned short* __restrict__ col) {
    __shared__ _Float16 shh[16][136];
    __shared__ float shc[16][132];
    __shared__ float smu[16], srs[16], sdo[16];
    __shared__ int smf[16];
    int t = threadIdx.x;
    int w = t >> 6, lane = t & 63;
    int rl = lane & 15, quad = lane >> 4;
    int r0 = blockIdx.x * 16;
    if (t < 16) {
        int r = r0 + t;
        sdo[t] = dinv_out[r];
        smf[t] = mflag[r];
    }
    GATHER16(r0 + lr)
    __syncthreads();
    // phase 2a: MFMA vs Wh2
    const half8* B0p = (const half8*)(Wh2 + (size_t)(w * 32 + rl) * 128 + quad * 8);
    const half8* B1p = (const half8*)(Wh2 + (size_t)(w * 32 + 16 + rl) * 128 + quad * 8);
    f32x4 c00 = {0.f, 0.f, 0.f, 0.f}, c01 = c00;
#pragma unroll
    for (int kk = 0; kk < 4; ++kk) {
        half8 a0 = *(const half8*)&shh[rl][kk * 32 + quad * 8];
        half8 b0 = B0p[kk * 4];
        half8 b1 = B1p[kk * 4];
        c00 = __builtin_amdgcn_mfma_f32_16x16x32_f16(a0, b0, c00, 0, 0, 0);
        c01 = __builtin_amdgcn_mfma_f32_16x16x32_f16(a0, b1, c01, 0, 0, 0);
    }
#pragma unroll
    for (int reg = 0; reg < 4; ++reg) {
        shc[quad * 4 + reg][w * 32 + rl] = c00[reg];
        shc[quad * 4 + reg][w * 32 + 16 + rl] = c01[reg];
    }
    __syncthreads();
    { // LN stats: 16 threads/row
        int row = t >> 4, seg = t & 15;
        float di = dinv_in[r0 + row];
        float s = 0.f, qq = 0.f;
#pragma unroll
        for (int c = 0; c < 8; ++c) {
            int cc = seg * 8 + c;
            float v = (shc[row][cc] + bias[cc]) * di;
            s += v;
            qq += v * v;
        }
#pragma unroll
        for (int o = 1; o <= 8; o <<= 1) {
            s += __shfl_xor(s, o);
            qq += __shfl_xor(qq, o);
        }
        if (seg == 0) {
            float mu = s * (1.f / 128.f);
            float var = qq * (1.f / 128.f) - mu * mu;
            smu[row] = mu;
            srs[row] = rsqrtf(var + 1e-5f);
        }
        __syncthreads();
    }
    { // h2 -> shh (fp16)
        int lane64 = t & 63, grp = t >> 6;
        int cc0 = lane64 * 2, cc1 = cc0 + 1;
        float bt0 = bias[cc0], bt1 = bias[cc1];
        float gt0 = g[cc0], gt1 = g[cc1];
        float be0 = be[cc0], be1 = be[cc1];
        float alpha = aP[0];
#pragma unroll
        for (int i = 0; i < 4; ++i) {
            int lr = grp * 4 + i, r = r0 + lr;
            float di = dinv_in[r];
            float v0 = (shc[lr][cc0] + bt0) * di;
            float v1 = (shc[lr][cc1] + bt1) * di;
            float mu = smu[lr], rs = srs[lr];
            v0 = (v0 - mu) * rs * gt0 + be0;
            v1 = (v1 - mu) * rs * gt1 + be1;
            v0 = v0 >= 0.f ? v0 : alpha * v0;
            v1 = v1 >= 0.f ? v1 : alpha * v1;
            shh[lr][cc0] = (_Float16)v0;
            shh[lr][cc1] = (_Float16)v1;
        }
    }
    __syncthreads();
    // phase 2b: rep = h2 @ We2d, register-direct epilogue
    const half8* E0p = (const half8*)(WhE + (size_t)(w * 32 + rl) * 128 + quad * 8);
    const half8* E1p = (const half8*)(WhE + (size_t)(w * 32 + 16 + rl) * 128 + quad * 8);
    f32x4 d00 = {0.f, 0.f, 0.f, 0.f}, d01 = d00;
#pragma unroll
    for (int kk = 0; kk < 4; ++kk) {
        half8 a0 = *(const half8*)&shh[rl][kk * 32 + quad * 8];
        half8 b0 = E0p[kk * 4];
        half8 b1 = E1p[kk * 4];
        d00 = __builtin_amdgcn_mfma_f32_16x16x32_f16(a0, b0, d00, 0, 0, 0);
        d01 = __builtin_amdgcn_mfma_f32_16x16x32_f16(a0, b1, d01, 0, 0, 0);
    }
#pragma unroll
    for (int reg = 0; reg < 4; ++reg) {
        int lr = quad * 4 + reg, r = r0 + lr;
        float s = smf[lr] ? 0.f : sdo[lr];
        outh[(size_t)r * 128 + w * 32 + rl] = (_Float16)(d00[reg] * s);
        outh[(size_t)r * 128 + w * 32 + 16 + rl] = (_Float16)(d01[reg] * s);
    }
}

// ---------------- fused conv3-SpMM + decoder fc + SCE loss (16-row) ----------

__launch_bounds__(256)
__global__ void k_spmf_loss(const half8* __restrict__ Ah8, const float* __restrict__ x,
                            const _Float16* __restrict__ Wh, const float* __restrict__ bd,
                            const int* __restrict__ deg, const unsigned short* __restrict__ col,
                            const float* __restrict__ dinv_in,
                            const int* __restrict__ mask_nodes, float* __restrict__ outp) {
    __shared__ _Float16 shh[16][136];
    __shared__ float shc[16][132];
    __shared__ int shm[16];
    __shared__ float sterm[16];
    int t = threadIdx.x;
    int w = t >> 6, lane = t & 63;
    int rl = lane & 15, quad = lane >> 4;
    int i0 = blockIdx.x * 16;
    if (t < 16) {
        int idx = i0 + t;
        shm[t] = idx < MASKN ? mask_nodes[idx] : -1;
    }
    __syncthreads();
    GATHER16(shm[lr])
    __syncthreads();
    const half8* B0p = (const half8*)(Wh + (size_t)(w * 32 + rl) * 128 + quad * 8);
    const half8* B1p = (const half8*)(Wh + (size_t)(w * 32 + 16 + rl) * 128 + quad * 8);
    f32x4 c00 = {0.f, 0.f, 0.f, 0.f}, c01 = c00;
#pragma unroll
    for (int kk = 0; kk < 4; ++kk) {
        half8 a0 = *(const half8*)&shh[rl][kk * 32 + quad * 8];
        half8 b0 = B0p[kk * 4];
        half8 b1 = B1p[kk * 4];
        c00 = __builtin_amdgcn_mfma_f32_16x16x32_f16(a0, b0, c00, 0, 0, 0);
        c01 = __builtin_amdgcn_mfma_f32_16x16x32_f16(a0, b1, c01, 0, 0, 0);
    }
#pragma unroll
    for (int reg = 0; reg < 4; ++reg) {
        shc[quad * 4 + reg][w * 32 + rl] = c00[reg];
        shc[quad * 4 + reg][w * 32 + 16 + rl] = c01[reg];
    }
    __syncthreads();
    int row = t >> 4, seg = t & 15; // 16 threads/row, 8 cols each
    int m = shm[row];
    float a = 0.f, b = 0.f, c = 0.f;
    if (m >= 0) {
        float di = dinv_in[m];
#pragma unroll
        for (int cc0 = 0; cc0 < 8; ++cc0) {
            int cc = seg * 8 + cc0;
            float r = (shc[row][cc] + bd[cc]) * di;
            float xv = x[(size_t)m * 128 + cc];
            a += r * r;
            b += xv * xv;
            c += r * xv;
        }
    }
#pragma unroll
    for (int o = 1; o <= 8; o <<= 1) {
        a += __shfl_xor(a, o);
        b += __shfl_xor(b, o);
        c += __shfl_xor(c, o);
    }
    if (seg == 0) {
        float term = 0.f;
        if (m >= 0) {
            float nr = fmaxf(sqrtf(a), 1e-12f);
            float nx = fmaxf(sqrtf(b), 1e-12f);
            float d = 1.f - c / (nr * nx);
            term = d * d;
        }
        sterm[row] = term;
    }
    __syncthreads();
    if (t == 0) {
        float sum = 0.f;
#pragma unroll
        for (int i = 0; i < 16; ++i) sum += sterm[i];
        atomicAdd(outp, sum * (1.f / MASKN));
    }
}

// ---------------- launch ----------------

extern "C" void kernel_launch(void* const* d_in, const int* in_sizes, int n_in,
                              void* d_out, int out_size, void* d_ws, size_t ws_size,
                              hipStream_t stream) {
    const float* x = (const float*)d_in[0];
    const float* tok = (const float*)d_in[1];
    const float* W1 = (const float*)d_in[2];
    const float* b1 = (const float*)d_in[3];
    const float* g1 = (const float*)d_in[4];
    const float* be1 = (const float*)d_in[5];
    const float* a1 = (const float*)d_in[6];
    const float* W2 = (const float*)d_in[7];
    const float* b2 = (const float*)d_in[8];
    const float* g2 = (const float*)d_in[9];
    const float* be2 = (const float*)d_in[10];
    const float* a2 = (const float*)d_in[11];
    const float* We2d = (const float*)d_in[12];
    const float* Wd = (const float*)d_in[13];
    const float* bd = (const float*)d_in[14];
    const int* src = (const int*)d_in[15];
    const int* dst = (const int*)d_in[16];
    const int* mask_nodes = (const int*)d_in[17];

    char* w = (char*)d_ws;
    _Float16* Ah = (_Float16*)w;        w += (size_t)N * D * 2;
    _Float16* Bh = (_Float16*)w;        w += (size_t)N * D * 2;
    unsigned short* col = (unsigned short*)w; w += (size_t)N * CAP * 2;
    int* cursor = (int*)w;              w += (size_t)N * 4; // becomes deg_in
    int* mflag = (int*)w;               w += (size_t)N * 4;
    float* dinv_out = (float*)w;        w += (size_t)N * 4;
    float* dinv_in = (float*)w;         w += (size_t)N * 4;
    _Float16* Wh1 = (_Float16*)w;       w += (size_t)D * D * 2;
    _Float16* Wh2 = (_Float16*)w;       w += (size_t)D * D * 2;
    _Float16* WhE = (_Float16*)w;       w += (size_t)D * D * 2;
    _Float16* WhD = (_Float16*)w;       w += (size_t)D * D * 2;
    unsigned int* partial = (unsigned int*)w; w += (size_t)HB * HW * 4;

    // zero cursor, mflag (contiguous 2*N ints) + output scalar
    hipMemsetAsync(cursor, 0, (size_t)2 * N * 4, stream);
    hipMemsetAsync(d_out, 0, sizeof(float), stream);

    k_build<<<(E + 255) / 256, 256, 0, stream>>>(src, dst, cursor, col);
    k_hist<<<HB, 256, 0, stream>>>(src, partial);
    k_misc<<<310, 256, 0, stream>>>(W1, W2, We2d, Wd, Wh1, Wh2, WhE, WhD,
                                    partial, cursor, dinv_out, dinv_in, mask_nodes, mflag);
    k_prep<<<(N * 32 + 255) / 256, 256, 0, stream>>>((const float4*)x, (const float4*)tok,
                                                     mflag, dinv_out, (half4*)Ah);
    int nmf = N / 16;               // 3125
    int nmfl = (MASKN + 15) / 16;   // 1563
    // conv1: agg + fc + LN + PReLU + pre-scale (fused) : Ah -> Bh
    k_spmf<true, true, false><<<nmf, 256, 0, stream>>>(
        (const half8*)Ah, Bh, Wh1, b1, g1, be1, a1, dinv_in, dinv_out, nullptr,
        cursor, col);
    // conv2: agg + fc/LN/PReLU + encoder_to_decoder + re-mask + pre-scale : Bh -> Ah
    k_spmf2<<<nmf, 256, 0, stream>>>(
        (const half8*)Bh, Ah, Wh2, WhE, b2, g2, be2, a2, dinv_in, dinv_out, mflag,
        cursor, col);
    // conv3 agg + decoder fc + SCE loss (fused)
    k_spmf_loss<<<nmfl, 256, 0, stream>>>((const half8*)Ah, x, WhD, bd, cursor, col,
                                          dinv_in, mask_nodes, (float*)d_out);
}

// Round 15
// 314.263 us; speedup vs baseline: 1.0233x; 1.0103x over previous
//
#include <hip/hip_runtime.h>

constexpr int N = 50000;
constexpr int E = 800000;
constexpr int D = 128;
constexpr int MASKN = 25000;
constexpr int CAP = 64; // bucket = exactly two 64B lines; deg~Poisson(16), 12 sigma
constexpr int HB = 128;           // histogram blocks
constexpr int HW = (N + 1) / 2;   // packed 2x16-bit words

typedef _Float16 half8 __attribute__((ext_vector_type(8)));
typedef _Float16 half4 __attribute__((ext_vector_type(4)));
typedef _Float16 half2v __attribute__((ext_vector_type(2)));
typedef float f32x4 __attribute__((ext_vector_type(4)));

#define ROW8(X) X(0) X(1) X(2) X(3) X(4) X(5) X(6) X(7)

// ---------------- bucket build: cursor atomic + scatter only ----------------

__global__ void k_build(const int* __restrict__ src, const int* __restrict__ dst,
                        int* __restrict__ cursor, unsigned short* __restrict__ col) {
    int e = blockIdx.x * blockDim.x + threadIdx.x;
    if (e < E) {
        int s = src[e], d = dst[e];
        int p = atomicAdd(&cursor[d], 1);
        col[(size_t)d * CAP + p] = (unsigned short)s;
    }
}

// ---------------- out-degree histogram: LDS-privatized, packed 2x16-bit ------

__launch_bounds__(256)
__global__ void k_hist(const int* __restrict__ src, unsigned int* __restrict__ partial) {
    __shared__ unsigned int hcnt[HW];
    int b = blockIdx.x, t = threadIdx.x;
    for (int i = t; i < HW; i += 256) hcnt[i] = 0u;
    __syncthreads();
    constexpr int PER = E / HB; // 6250
    int base = b * PER;
    for (int i = t; i < PER; i += 256) {
        int s = src[base + i];
        atomicAdd(&hcnt[s >> 1], 1u << ((s & 1) * 16));
    }
    __syncthreads();
    unsigned int* outp = partial + (size_t)b * HW;
    for (int i = t; i < HW; i += 256) outp[i] = hcnt[i];
}

// ---------------- fused setup: 4x W->fp16 cast + dinv (partial-sum) + mflag --

__global__ void k_misc(const float* __restrict__ W1, const float* __restrict__ W2,
                       const float* __restrict__ WE, const float* __restrict__ WD,
                       _Float16* __restrict__ Wh1, _Float16* __restrict__ Wh2,
                       _Float16* __restrict__ WhE, _Float16* __restrict__ WhD,
                       const unsigned int* __restrict__ partial,
                       const int* __restrict__ cd,
                       float* __restrict__ dinv_out, float* __restrict__ dinv_in,
                       const int* __restrict__ mask_nodes, int* __restrict__ mflag) {
    int b = blockIdx.x, t = threadIdx.x;
    if (b < 16) { // 4 matrices x 4 blocks, 4096 elems each
        int m = b >> 2;
        const float* W = m == 0 ? W1 : m == 1 ? W2 : m == 2 ? WE : WD;
        _Float16* Wh = m == 0 ? Wh1 : m == 1 ? Wh2 : m == 2 ? WhE : WhD;
        int base = (b & 3) * 4096 + t;
#pragma unroll
        for (int j = 0; j < 16; ++j) Wh[base + j * 256] = (_Float16)W[base + j * 256];
    } else if (b < 16 + 196) {
        int i = (b - 16) * 256 + t;
        if (i < N) {
            int word = i >> 1, sh = (i & 1) * 16;
            unsigned int sum = 0;
#pragma unroll 8
            for (int bb = 0; bb < HB; ++bb)
                sum += (partial[(size_t)bb * HW + word] >> sh) & 0xffffu;
            int a = sum > 1u ? (int)sum : 1;
            int bb2 = cd[i] > 1 ? cd[i] : 1;
            dinv_out[i] = rsqrtf((float)a);
            dinv_in[i] = rsqrtf((float)bb2);
        }
    } else {
        int i = (b - 212) * 256 + t;
        if (i < MASKN) mflag[mask_nodes[i]] = 1;
    }
}

// ---------------- feature prep: masked x scaled by deg_out^-0.5, fp16 out ----

__global__ void k_prep(const float4* __restrict__ x, const float4* __restrict__ tok,
                       const int* __restrict__ mflag, const float* __restrict__ dinv_out,
                       half4* __restrict__ Ah4) {
    int i = blockIdx.x * blockDim.x + threadIdx.x; // over N*32 float4s
    if (i < N * 32) {
        int row = i >> 5;
        int c = i & 31;
        float s = dinv_out[row];
        float4 v = mflag[row] ? tok[c] : x[i];
        half4 h;
        h[0] = (_Float16)(v.x * s);
        h[1] = (_Float16)(v.y * s);
        h[2] = (_Float16)(v.z * s);
        h[3] = (_Float16)(v.w * s);
        Ah4[i] = h;
    }
}

// ---------------- per-quad gather: one quad owns one row, 8 loads in flight --
// quad's 16 lanes (j) cover the 256B feature row; col reads are same-address
// broadcasts within the quad. 32 independent gather chains per wave.

__device__ __forceinline__ void gather_rowq(const half8* __restrict__ Ah8,
                                            const int* __restrict__ deg,
                                            const unsigned short* __restrict__ col,
                                            int row, int j,
                                            float& a0, float& a1, float& a2, float& a3,
                                            float& a4, float& a5, float& a6, float& a7) {
    int dg = deg[row];
    const unsigned short* crow = col + (size_t)row * CAP;
    int e = 0;
    for (; e + 8 <= dg; e += 8) {
        int c0 = crow[e], c1 = crow[e + 1], c2 = crow[e + 2], c3 = crow[e + 3];
        int c4 = crow[e + 4], c5 = crow[e + 5], c6 = crow[e + 6], c7 = crow[e + 7];
        half8 h0 = Ah8[(size_t)c0 * 16 + j];
        half8 h1 = Ah8[(size_t)c1 * 16 + j];
        half8 h2 = Ah8[(size_t)c2 * 16 + j];
        half8 h3 = Ah8[(size_t)c3 * 16 + j];
        half8 h4 = Ah8[(size_t)c4 * 16 + j];
        half8 h5 = Ah8[(size_t)c5 * 16 + j];
        half8 h6 = Ah8[(size_t)c6 * 16 + j];
        half8 h7 = Ah8[(size_t)c7 * 16 + j];
#define SP_ACC8(i)                                                             \
        a##i += (float)h0[i]; a##i += (float)h1[i];                            \
        a##i += (float)h2[i]; a##i += (float)h3[i];                            \
        a##i += (float)h4[i]; a##i += (float)h5[i];                            \
        a##i += (float)h6[i]; a##i += (float)h7[i];
        ROW8(SP_ACC8)
#undef SP_ACC8
    }
    for (; e + 2 <= dg; e += 2) {
        int c0 = crow[e], c1 = crow[e + 1];
        half8 h0 = Ah8[(size_t)c0 * 16 + j];
        half8 h1 = Ah8[(size_t)c1 * 16 + j];
#define SP_ACC2(i) a##i += (float)h0[i]; a##i += (float)h1[i];
        ROW8(SP_ACC2)
#undef SP_ACC2
    }
    if (e < dg) {
        int c0 = crow[e];
        half8 h0 = Ah8[(size_t)c0 * 16 + j];
#define SP_ACC1(i) a##i += (float)h0[i];
        ROW8(SP_ACC1)
#undef SP_ACC1
    }
}

// gather 16-row tile: wave w, quad -> row w*4+quad; no shuffles, direct store.
#define GATHERQ(ROWEXPR)                                                       \
    {                                                                          \
        int lr = w * 4 + quad;                                                 \
        int row = ROWEXPR;                                                     \
        float a0 = 0.f, a1 = 0.f, a2 = 0.f, a3 = 0.f;                          \
        float a4 = 0.f, a5 = 0.f, a6 = 0.f, a7 = 0.f;                          \
        if (row >= 0)                                                          \
            gather_rowq(Ah8, deg, col, row, rl, a0, a1, a2, a3, a4, a5, a6, a7); \
        half8 ho;                                                              \
        ho[0] = (_Float16)a0; ho[1] = (_Float16)a1;                            \
        ho[2] = (_Float16)a2; ho[3] = (_Float16)a3;                            \
        ho[4] = (_Float16)a4; ho[5] = (_Float16)a5;                            \
        ho[6] = (_Float16)a6; ho[7] = (_Float16)a7;                            \
        *(half8*)&shh[lr][rl * 8] = ho;                                        \
    }

// ---------------- fused SpMM + MFMA fc + LN/PReLU epilogue (16-row tile) -----

template <bool LN, bool SCALE_OUT, bool MASK_ZERO>
__launch_bounds__(256)
__global__ void k_spmf(const half8* __restrict__ Ah8, _Float16* __restrict__ outh,
                       const _Float16* __restrict__ Wh,
                       const float* __restrict__ bias, const float* __restrict__ g,
                       const float* __restrict__ be, const float* __restrict__ aP,
                       const float* __restrict__ dinv_in, const float* __restrict__ dinv_out,
                       const int* __restrict__ mflag,
                       const int* __restrict__ deg, const unsigned short* __restrict__ col) {
    __shared__ _Float16 shh[16][136];
    __shared__ float shc[16][132];
    __shared__ float smu[16], srs[16];
    int t = threadIdx.x;
    int w = t >> 6, lane = t & 63;
    int rl = lane & 15, quad = lane >> 4;
    int r0 = blockIdx.x * 16; // N % 16 == 0
    GATHERQ(r0 + lr)
    __syncthreads();
    const half8* B0p = (const half8*)(Wh + (size_t)(w * 32 + rl) * 128 + quad * 8);
    const half8* B1p = (const half8*)(Wh + (size_t)(w * 32 + 16 + rl) * 128 + quad * 8);
    f32x4 c00 = {0.f, 0.f, 0.f, 0.f}, c01 = c00;
#pragma unroll
    for (int kk = 0; kk < 4; ++kk) {
        half8 a0 = *(const half8*)&shh[rl][kk * 32 + quad * 8];
        half8 b0 = B0p[kk * 4];
        half8 b1 = B1p[kk * 4];
        c00 = __builtin_amdgcn_mfma_f32_16x16x32_f16(a0, b0, c00, 0, 0, 0);
        c01 = __builtin_amdgcn_mfma_f32_16x16x32_f16(a0, b1, c01, 0, 0, 0);
    }
#pragma unroll
    for (int reg = 0; reg < 4; ++reg) {
        shc[quad * 4 + reg][w * 32 + rl] = c00[reg];
        shc[quad * 4 + reg][w * 32 + 16 + rl] = c01[reg];
    }
    __syncthreads();
    if constexpr (LN) {
        int row = t >> 4, seg = t & 15; // 16 threads/row, 8 cols each
        float di = dinv_in[r0 + row];
        float s = 0.f, qq = 0.f;
#pragma unroll
        for (int c = 0; c < 8; ++c) {
            int cc = seg * 8 + c;
            float v = (shc[row][cc] + bias[cc]) * di;
            s += v;
            qq += v * v;
        }
#pragma unroll
        for (int o = 1; o <= 8; o <<= 1) {
            s += __shfl_xor(s, o);
            qq += __shfl_xor(qq, o);
        }
        if (seg == 0) {
            float mu = s * (1.f / 128.f);
            float var = qq * (1.f / 128.f) - mu * mu;
            smu[row] = mu;
            srs[row] = rsqrtf(var + 1e-5f);
        }
        __syncthreads();
    }
    int lane64 = t & 63, grp = t >> 6;
    int cc0 = lane64 * 2, cc1 = cc0 + 1;
    float bt0 = 0.f, bt1 = 0.f, gt0 = 0.f, gt1 = 0.f, be0 = 0.f, be1 = 0.f, alpha = 0.f;
    if constexpr (LN) {
        bt0 = bias[cc0]; bt1 = bias[cc1];
        gt0 = g[cc0]; gt1 = g[cc1];
        be0 = be[cc0]; be1 = be[cc1];
        alpha = aP[0];
    }
#pragma unroll
    for (int i = 0; i < 4; ++i) {
        int lr = grp * 4 + i, r = r0 + lr;
        float v0 = shc[lr][cc0], v1 = shc[lr][cc1];
        if constexpr (LN) {
            float di = dinv_in[r];
            v0 = (v0 + bt0) * di;
            v1 = (v1 + bt1) * di;
            float mu = smu[lr], rs = srs[lr];
            v0 = (v0 - mu) * rs * gt0 + be0;
            v1 = (v1 - mu) * rs * gt1 + be1;
            v0 = v0 >= 0.f ? v0 : alpha * v0;
            v1 = v1 >= 0.f ? v1 : alpha * v1;
        }
        if (MASK_ZERO && mflag[r]) { v0 = 0.f; v1 = 0.f; }
        if constexpr (SCALE_OUT) {
            float so = dinv_out[r];
            v0 *= so; v1 *= so;
        }
        half2v hv;
        hv[0] = (_Float16)v0;
        hv[1] = (_Float16)v1;
        *(half2v*)(outh + (size_t)r * 128 + cc0) = hv;
    }
}

// ---------------- fused SpMM + conv2-fc/LN + encoder_to_decoder (16-row) -----

__launch_bounds__(256)
__global__ void k_spmf2(const half8* __restrict__ Ah8, _Float16* __restrict__ outh,
                        const _Float16* __restrict__ Wh2, const _Float16* __restrict__ WhE,
                        const float* __restrict__ bias, const float* __restrict__ g,
                        const float* __restrict__ be, const float* __restrict__ aP,
                        const float* __restrict__ dinv_in, const float* __restrict__ dinv_out,
                        const int* __restrict__ mflag,
                        const int* __restrict__ deg, const unsigned short* __restrict__ col) {
    __shared__ _Float16 shh[16][136];
    __shared__ float shc[16][132];
    __shared__ float smu[16], srs[16], sdo[16];
    __shared__ int smf[16];
    int t = threadIdx.x;
    int w = t >> 6, lane = t & 63;
    int rl = lane & 15, quad = lane >> 4;
    int r0 = blockIdx.x * 16;
    if (t < 16) {
        int r = r0 + t;
        sdo[t] = dinv_out[r];
        smf[t] = mflag[r];
    }
    GATHERQ(r0 + lr)
    __syncthreads();
    const half8* B0p = (const half8*)(Wh2 + (size_t)(w * 32 + rl) * 128 + quad * 8);
    const half8* B1p = (const half8*)(Wh2 + (size_t)(w * 32 + 16 + rl) * 128 + quad * 8);
    f32x4 c00 = {0.f, 0.f, 0.f, 0.f}, c01 = c00;
#pragma unroll
    for (int kk = 0; kk < 4; ++kk) {
        half8 a0 = *(const half8*)&shh[rl][kk * 32 + quad * 8];
        half8 b0 = B0p[kk * 4];
        half8 b1 = B1p[kk * 4];
        c00 = __builtin_amdgcn_mfma_f32_16x16x32_f16(a0, b0, c00, 0, 0, 0);
        c01 = __builtin_amdgcn_mfma_f32_16x16x32_f16(a0, b1, c01, 0, 0, 0);
    }
#pragma unroll
    for (int reg = 0; reg < 4; ++reg) {
        shc[quad * 4 + reg][w * 32 + rl] = c00[reg];
        shc[quad * 4 + reg][w * 32 + 16 + rl] = c01[reg];
    }
    __syncthreads();
    { // LN stats: 16 threads/row
        int row = t >> 4, seg = t & 15;
        float di = dinv_in[r0 + row];
        float s = 0.f, qq = 0.f;
#pragma unroll
        for (int c = 0; c < 8; ++c) {
            int cc = seg * 8 + c;
            float v = (shc[row][cc] + bias[cc]) * di;
            s += v;
            qq += v * v;
        }
#pragma unroll
        for (int o = 1; o <= 8; o <<= 1) {
            s += __shfl_xor(s, o);
            qq += __shfl_xor(qq, o);
        }
        if (seg == 0) {
            float mu = s * (1.f / 128.f);
            float var = qq * (1.f / 128.f) - mu * mu;
            smu[row] = mu;
            srs[row] = rsqrtf(var + 1e-5f);
        }
        __syncthreads();
    }
    { // h2 -> shh (fp16)
        int lane64 = t & 63, grp = t >> 6;
        int cc0 = lane64 * 2, cc1 = cc0 + 1;
        float bt0 = bias[cc0], bt1 = bias[cc1];
        float gt0 = g[cc0], gt1 = g[cc1];
        float be0 = be[cc0], be1 = be[cc1];
        float alpha = aP[0];
#pragma unroll
        for (int i = 0; i < 4; ++i) {
            int lr = grp * 4 + i, r = r0 + lr;
            float di = dinv_in[r];
            float v0 = (shc[lr][cc0] + bt0) * di;
            float v1 = (shc[lr][cc1] + bt1) * di;
            float mu = smu[lr], rs = srs[lr];
            v0 = (v0 - mu) * rs * gt0 + be0;
            v1 = (v1 - mu) * rs * gt1 + be1;
            v0 = v0 >= 0.f ? v0 : alpha * v0;
            v1 = v1 >= 0.f ? v1 : alpha * v1;
            shh[lr][cc0] = (_Float16)v0;
            shh[lr][cc1] = (_Float16)v1;
        }
    }
    __syncthreads();
    const half8* E0p = (const half8*)(WhE + (size_t)(w * 32 + rl) * 128 + quad * 8);
    const half8* E1p = (const half8*)(WhE + (size_t)(w * 32 + 16 + rl) * 128 + quad * 8);
    f32x4 d00 = {0.f, 0.f, 0.f, 0.f}, d01 = d00;
#pragma unroll
    for (int kk = 0; kk < 4; ++kk) {
        half8 a0 = *(const half8*)&shh[rl][kk * 32 + quad * 8];
        half8 b0 = E0p[kk * 4];
        half8 b1 = E1p[kk * 4];
        d00 = __builtin_amdgcn_mfma_f32_16x16x32_f16(a0, b0, d00, 0, 0, 0);
        d01 = __builtin_amdgcn_mfma_f32_16x16x32_f16(a0, b1, d01, 0, 0, 0);
    }
#pragma unroll
    for (int reg = 0; reg < 4; ++reg) {
        int lr = quad * 4 + reg, r = r0 + lr;
        float s = smf[lr] ? 0.f : sdo[lr];
        outh[(size_t)r * 128 + w * 32 + rl] = (_Float16)(d00[reg] * s);
        outh[(size_t)r * 128 + w * 32 + 16 + rl] = (_Float16)(d01[reg] * s);
    }
}

// ---------------- fused conv3-SpMM + decoder fc + SCE loss (16-row) ----------

__launch_bounds__(256)
__global__ void k_spmf_loss(const half8* __restrict__ Ah8, const float* __restrict__ x,
                            const _Float16* __restrict__ Wh, const float* __restrict__ bd,
                            const int* __restrict__ deg, const unsigned short* __restrict__ col,
                            const float* __restrict__ dinv_in,
                            const int* __restrict__ mask_nodes, float* __restrict__ outp) {
    __shared__ _Float16 shh[16][136];
    __shared__ float shc[16][132];
    __shared__ int shm[16];
    __shared__ float sterm[16];
    int t = threadIdx.x;
    int w = t >> 6, lane = t & 63;
    int rl = lane & 15, quad = lane >> 4;
    int i0 = blockIdx.x * 16;
    if (t < 16) {
        int idx = i0 + t;
        shm[t] = idx < MASKN ? mask_nodes[idx] : -1;
    }
    __syncthreads();
    GATHERQ(shm[lr])
    __syncthreads();
    const half8* B0p = (const half8*)(Wh + (size_t)(w * 32 + rl) * 128 + quad * 8);
    const half8* B1p = (const half8*)(Wh + (size_t)(w * 32 + 16 + rl) * 128 + quad * 8);
    f32x4 c00 = {0.f, 0.f, 0.f, 0.f}, c01 = c00;
#pragma unroll
    for (int kk = 0; kk < 4; ++kk) {
        half8 a0 = *(const half8*)&shh[rl][kk * 32 + quad * 8];
        half8 b0 = B0p[kk * 4];
        half8 b1 = B1p[kk * 4];
        c00 = __builtin_amdgcn_mfma_f32_16x16x32_f16(a0, b0, c00, 0, 0, 0);
        c01 = __builtin_amdgcn_mfma_f32_16x16x32_f16(a0, b1, c01, 0, 0, 0);
    }
#pragma unroll
    for (int reg = 0; reg < 4; ++reg) {
        shc[quad * 4 + reg][w * 32 + rl] = c00[reg];
        shc[quad * 4 + reg][w * 32 + 16 + rl] = c01[reg];
    }
    __syncthreads();
    int row = t >> 4, seg = t & 15; // 16 threads/row, 8 cols each
    int m = shm[row];
    float a = 0.f, b = 0.f, c = 0.f;
    if (m >= 0) {
        float di = dinv_in[m];
#pragma unroll
        for (int cc0 = 0; cc0 < 8; ++cc0) {
            int cc = seg * 8 + cc0;
            float r = (shc[row][cc] + bd[cc]) * di;
            float xv = x[(size_t)m * 128 + cc];
            a += r * r;
            b += xv * xv;
            c += r * xv;
        }
    }
#pragma unroll
    for (int o = 1; o <= 8; o <<= 1) {
        a += __shfl_xor(a, o);
        b += __shfl_xor(b, o);
        c += __shfl_xor(c, o);
    }
    if (seg == 0) {
        float term = 0.f;
        if (m >= 0) {
            float nr = fmaxf(sqrtf(a), 1e-12f);
            float nx = fmaxf(sqrtf(b), 1e-12f);
            float d = 1.f - c / (nr * nx);
            term = d * d;
        }
        sterm[row] = term;
    }
    __syncthreads();
    if (t == 0) {
        float sum = 0.f;
#pragma unroll
        for (int i = 0; i < 16; ++i) sum += sterm[i];
        atomicAdd(outp, sum * (1.f / MASKN));
    }
}

// ---------------- launch ----------------

extern "C" void kernel_launch(void* const* d_in, const int* in_sizes, int n_in,
                              void* d_out, int out_size, void* d_ws, size_t ws_size,
                              hipStream_t stream) {
    const float* x = (const float*)d_in[0];
    const float* tok = (const float*)d_in[1];
    const float* W1 = (const float*)d_in[2];
    const float* b1 = (const float*)d_in[3];
    const float* g1 = (const float*)d_in[4];
    const float* be1 = (const float*)d_in[5];
    const float* a1 = (const float*)d_in[6];
    const float* W2 = (const float*)d_in[7];
    const float* b2 = (const float*)d_in[8];
    const float* g2 = (const float*)d_in[9];
    const float* be2 = (const float*)d_in[10];
    const float* a2 = (const float*)d_in[11];
    const float* We2d = (const float*)d_in[12];
    const float* Wd = (const float*)d_in[13];
    const float* bd = (const float*)d_in[14];
    const int* src = (const int*)d_in[15];
    const int* dst = (const int*)d_in[16];
    const int* mask_nodes = (const int*)d_in[17];

    char* w = (char*)d_ws;
    _Float16* Ah = (_Float16*)w;        w += (size_t)N * D * 2;
    _Float16* Bh = (_Float16*)w;        w += (size_t)N * D * 2;
    unsigned short* col = (unsigned short*)w; w += (size_t)N * CAP * 2;
    int* cursor = (int*)w;              w += (size_t)N * 4; // becomes deg_in
    int* mflag = (int*)w;               w += (size_t)N * 4;
    float* dinv_out = (float*)w;        w += (size_t)N * 4;
    float* dinv_in = (float*)w;         w += (size_t)N * 4;
    _Float16* Wh1 = (_Float16*)w;       w += (size_t)D * D * 2;
    _Float16* Wh2 = (_Float16*)w;       w += (size_t)D * D * 2;
    _Float16* WhE = (_Float16*)w;       w += (size_t)D * D * 2;
    _Float16* WhD = (_Float16*)w;       w += (size_t)D * D * 2;
    unsigned int* partial = (unsigned int*)w; w += (size_t)HB * HW * 4;

    // zero cursor, mflag (contiguous 2*N ints) + output scalar
    hipMemsetAsync(cursor, 0, (size_t)2 * N * 4, stream);
    hipMemsetAsync(d_out, 0, sizeof(float), stream);

    k_build<<<(E + 255) / 256, 256, 0, stream>>>(src, dst, cursor, col);
    k_hist<<<HB, 256, 0, stream>>>(src, partial);
    k_misc<<<310, 256, 0, stream>>>(W1, W2, We2d, Wd, Wh1, Wh2, WhE, WhD,
                                    partial, cursor, dinv_out, dinv_in, mask_nodes, mflag);
    k_prep<<<(N * 32 + 255) / 256, 256, 0, stream>>>((const float4*)x, (const float4*)tok,
                                                     mflag, dinv_out, (half4*)Ah);
    int nmf = N / 16;               // 3125
    int nmfl = (MASKN + 15) / 16;   // 1563
    // conv1: agg + fc + LN + PReLU + pre-scale (fused) : Ah -> Bh
    k_spmf<true, true, false><<<nmf, 256, 0, stream>>>(
        (const half8*)Ah, Bh, Wh1, b1, g1, be1, a1, dinv_in, dinv_out, nullptr,
        cursor, col);
    // conv2: agg + fc/LN/PReLU + encoder_to_decoder + re-mask + pre-scale : Bh -> Ah
    k_spmf2<<<nmf, 256, 0, stream>>>(
        (const half8*)Bh, Ah, Wh2, WhE, b2, g2, be2, a2, dinv_in, dinv_out, mflag,
        cursor, col);
    // conv3 agg + decoder fc + SCE loss (fused)
    k_spmf_loss<<<nmfl, 256, 0, stream>>>((const half8*)Ah, x, WhD, bd, cursor, col,
                                          dinv_in, mask_nodes, (float*)d_out);
}

// Round 16
// 309.775 us; speedup vs baseline: 1.0381x; 1.0145x over previous
//
#include <hip/hip_runtime.h>

constexpr int N = 50000;
constexpr int E = 800000;
constexpr int D = 128;
constexpr int MASKN = 25000;
constexpr int CAP = 64; // bucket = exactly two 64B lines; deg~Poisson(16), 12 sigma
constexpr int HB = 128;           // histogram blocks
constexpr int HW = (N + 1) / 2;   // packed 2x16-bit words

typedef _Float16 half8 __attribute__((ext_vector_type(8)));
typedef _Float16 half4 __attribute__((ext_vector_type(4)));
typedef _Float16 half2v __attribute__((ext_vector_type(2)));
typedef float f32x4 __attribute__((ext_vector_type(4)));

#define ROW8(X) X(0) X(1) X(2) X(3) X(4) X(5) X(6) X(7)

// ---------------- merged setup: bucket build + W->fp16 cast + mflag ----------
// build (atomic-latency-bound) overlaps with the small streaming jobs.

constexpr int NB_BUILD = (E + 255) / 256;     // 3125
constexpr int NB_CAST = 16;
constexpr int NB_MFLAG = (MASKN + 255) / 256; // 98

__global__ void k_setup(const int* __restrict__ src, const int* __restrict__ dst,
                        int* __restrict__ cursor, unsigned short* __restrict__ col,
                        const float* __restrict__ W1, const float* __restrict__ W2,
                        const float* __restrict__ WE, const float* __restrict__ WD,
                        _Float16* __restrict__ Wh1, _Float16* __restrict__ Wh2,
                        _Float16* __restrict__ WhE, _Float16* __restrict__ WhD,
                        const int* __restrict__ mask_nodes, int* __restrict__ mflag) {
    int b = blockIdx.x, t = threadIdx.x;
    if (b < NB_BUILD) {
        int e = b * 256 + t;
        if (e < E) {
            int s = src[e], d = dst[e];
            int p = atomicAdd(&cursor[d], 1);
            col[(size_t)d * CAP + p] = (unsigned short)s;
        }
    } else if (b < NB_BUILD + NB_CAST) {
        int b2 = b - NB_BUILD;
        int m = b2 >> 2;
        const float* W = m == 0 ? W1 : m == 1 ? W2 : m == 2 ? WE : WD;
        _Float16* Wh = m == 0 ? Wh1 : m == 1 ? Wh2 : m == 2 ? WhE : WhD;
        int base = (b2 & 3) * 4096 + t;
#pragma unroll
        for (int j = 0; j < 16; ++j) Wh[base + j * 256] = (_Float16)W[base + j * 256];
    } else {
        int i = (b - NB_BUILD - NB_CAST) * 256 + t;
        if (i < MASKN) mflag[mask_nodes[i]] = 1;
    }
}

// ---------------- out-degree histogram: LDS-privatized, packed 2x16-bit ------

__launch_bounds__(256)
__global__ void k_hist(const int* __restrict__ src, unsigned int* __restrict__ partial) {
    __shared__ unsigned int hcnt[HW];
    int b = blockIdx.x, t = threadIdx.x;
    for (int i = t; i < HW; i += 256) hcnt[i] = 0u;
    __syncthreads();
    constexpr int PER = E / HB; // 6250
    int base = b * PER;
    for (int i = t; i < PER; i += 256) {
        int s = src[base + i];
        atomicAdd(&hcnt[s >> 1], 1u << ((s & 1) * 16));
    }
    __syncthreads();
    unsigned int* outp = partial + (size_t)b * HW;
    for (int i = t; i < HW; i += 256) outp[i] = hcnt[i];
}

// ---------------- fused dinv(from partials) + feature prep ------------------
// 32 rows/block: sum the 128 histogram partials for our 16 packed words,
// compute dinv_out/in, then prep 32 feature rows -> fp16.

__launch_bounds__(256)
__global__ void k_prep2(const float4* __restrict__ x, const float4* __restrict__ tok,
                        const unsigned int* __restrict__ partial,
                        const int* __restrict__ cursor,
                        const int* __restrict__ mflag,
                        float* __restrict__ dinv_out, float* __restrict__ dinv_in,
                        half4* __restrict__ Ah4) {
    __shared__ unsigned int sred[16][17];
    __shared__ float sdo[32];
    __shared__ int smf[32];
    int b = blockIdx.x, t = threadIdx.x;
    int w0 = b * 16; // first packed word
    { // phase A: histogram partial sums
        int g = t >> 4, wi = t & 15;
        int wd = w0 + wi;
        unsigned int s = 0;
        if (wd < HW) {
#pragma unroll
            for (int k = 0; k < 8; ++k)
                s += partial[(size_t)(g + 16 * k) * HW + wd];
        }
        sred[g][wi] = s;
    }
    __syncthreads();
    if (t < 16) {
        unsigned int tot = 0;
#pragma unroll
        for (int g = 0; g < 16; ++g) tot += sred[g][t];
        int wd = w0 + t;
#pragma unroll
        for (int h = 0; h < 2; ++h) {
            int r = 2 * wd + h;
            if (r < N) {
                unsigned int dg = (tot >> (h * 16)) & 0xffffu;
                float dov = rsqrtf((float)(dg > 1u ? dg : 1u));
                int din = cursor[r];
                dinv_out[r] = dov;
                dinv_in[r] = rsqrtf((float)(din > 1 ? din : 1));
                sdo[2 * t + h] = dov;
                smf[2 * t + h] = mflag[r];
            }
        }
    }
    __syncthreads();
    // phase B: prep 32 rows
#pragma unroll
    for (int jj = 0; jj < 4; ++jj) {
        int fidx = t + 256 * jj; // 0..1023
        int lrow = fidx >> 5, c = fidx & 31;
        int r = b * 32 + lrow;
        if (r < N) {
            float s = sdo[lrow];
            float4 v = smf[lrow] ? tok[c] : x[(size_t)r * 32 + c];
            half4 h;
            h[0] = (_Float16)(v.x * s);
            h[1] = (_Float16)(v.y * s);
            h[2] = (_Float16)(v.z * s);
            h[3] = (_Float16)(v.w * s);
            Ah4[(size_t)r * 32 + c] = h;
        }
    }
}

// ---------------- per-quad gather: one quad owns one row, 8 loads in flight --

__device__ __forceinline__ void gather_rowq(const half8* __restrict__ Ah8,
                                            const int* __restrict__ deg,
                                            const unsigned short* __restrict__ col,
                                            int row, int j,
                                            float& a0, float& a1, float& a2, float& a3,
                                            float& a4, float& a5, float& a6, float& a7) {
    int dg = deg[row];
    const unsigned short* crow = col + (size_t)row * CAP;
    int e = 0;
    for (; e + 8 <= dg; e += 8) {
        int c0 = crow[e], c1 = crow[e + 1], c2 = crow[e + 2], c3 = crow[e + 3];
        int c4 = crow[e + 4], c5 = crow[e + 5], c6 = crow[e + 6], c7 = crow[e + 7];
        half8 h0 = Ah8[(size_t)c0 * 16 + j];
        half8 h1 = Ah8[(size_t)c1 * 16 + j];
        half8 h2 = Ah8[(size_t)c2 * 16 + j];
        half8 h3 = Ah8[(size_t)c3 * 16 + j];
        half8 h4 = Ah8[(size_t)c4 * 16 + j];
        half8 h5 = Ah8[(size_t)c5 * 16 + j];
        half8 h6 = Ah8[(size_t)c6 * 16 + j];
        half8 h7 = Ah8[(size_t)c7 * 16 + j];
#define SP_ACC8(i)                                                             \
        a##i += (float)h0[i]; a##i += (float)h1[i];                            \
        a##i += (float)h2[i]; a##i += (float)h3[i];                            \
        a##i += (float)h4[i]; a##i += (float)h5[i];                            \
        a##i += (float)h6[i]; a##i += (float)h7[i];
        ROW8(SP_ACC8)
#undef SP_ACC8
    }
    for (; e + 2 <= dg; e += 2) {
        int c0 = crow[e], c1 = crow[e + 1];
        half8 h0 = Ah8[(size_t)c0 * 16 + j];
        half8 h1 = Ah8[(size_t)c1 * 16 + j];
#define SP_ACC2(i) a##i += (float)h0[i]; a##i += (float)h1[i];
        ROW8(SP_ACC2)
#undef SP_ACC2
    }
    if (e < dg) {
        int c0 = crow[e];
        half8 h0 = Ah8[(size_t)c0 * 16 + j];
#define SP_ACC1(i) a##i += (float)h0[i];
        ROW8(SP_ACC1)
#undef SP_ACC1
    }
}

// 16-row tile, 128 threads (2 waves, 8 quads): quad qid gathers rows qid*2,+1.
#define GATHERQ2(ROWEXPR)                                                      \
    for (int rr = 0; rr < 2; ++rr) {                                           \
        int lr = qid * 2 + rr;                                                 \
        int row = ROWEXPR;                                                     \
        float a0 = 0.f, a1 = 0.f, a2 = 0.f, a3 = 0.f;                          \
        float a4 = 0.f, a5 = 0.f, a6 = 0.f, a7 = 0.f;                          \
        if (row >= 0)                                                          \
            gather_rowq(Ah8, deg, col, row, rl, a0, a1, a2, a3, a4, a5, a6, a7); \
        half8 ho;                                                              \
        ho[0] = (_Float16)a0; ho[1] = (_Float16)a1;                            \
        ho[2] = (_Float16)a2; ho[3] = (_Float16)a3;                            \
        ho[4] = (_Float16)a4; ho[5] = (_Float16)a5;                            \
        ho[6] = (_Float16)a6; ho[7] = (_Float16)a7;                            \
        *(half8*)&shh[lr][rl * 8] = ho;                                        \
    }

// wave w covers cols [w*64, w*64+64) as 4 col-tiles; verified MFMA layout (R10).
#define MFMA_PHASE(Wsrc, d0, d1, d2, d3)                                       \
    {                                                                          \
        const half8* P0 = (const half8*)(Wsrc + (size_t)(w * 64 + rl) * 128 + quad4 * 8);        \
        const half8* P1 = (const half8*)(Wsrc + (size_t)(w * 64 + 16 + rl) * 128 + quad4 * 8);   \
        const half8* P2 = (const half8*)(Wsrc + (size_t)(w * 64 + 32 + rl) * 128 + quad4 * 8);   \
        const half8* P3 = (const half8*)(Wsrc + (size_t)(w * 64 + 48 + rl) * 128 + quad4 * 8);   \
        _Pragma("unroll") for (int kk = 0; kk < 4; ++kk) {                     \
            half8 a0 = *(const half8*)&shh[rl][kk * 32 + quad4 * 8];           \
            half8 b0 = P0[kk * 4];                                             \
            half8 b1 = P1[kk * 4];                                             \
            half8 b2 = P2[kk * 4];                                             \
            half8 b3 = P3[kk * 4];                                             \
            d0 = __builtin_amdgcn_mfma_f32_16x16x32_f16(a0, b0, d0, 0, 0, 0);  \
            d1 = __builtin_amdgcn_mfma_f32_16x16x32_f16(a0, b1, d1, 0, 0, 0);  \
            d2 = __builtin_amdgcn_mfma_f32_16x16x32_f16(a0, b2, d2, 0, 0, 0);  \
            d3 = __builtin_amdgcn_mfma_f32_16x16x32_f16(a0, b3, d3, 0, 0, 0);  \
        }                                                                      \
    }

#define STORE_SHC(d0, d1, d2, d3)                                              \
    _Pragma("unroll") for (int reg = 0; reg < 4; ++reg) {                      \
        shc[quad4 * 4 + reg][w * 64 + rl] = d0[reg];                           \
        shc[quad4 * 4 + reg][w * 64 + 16 + rl] = d1[reg];                      \
        shc[quad4 * 4 + reg][w * 64 + 32 + rl] = d2[reg];                      \
        shc[quad4 * 4 + reg][w * 64 + 48 + rl] = d3[reg];                      \
    }

// ---------------- fused SpMM + MFMA fc + LN/PReLU epilogue -------------------

template <bool LN, bool SCALE_OUT, bool MASK_ZERO>
__launch_bounds__(128)
__global__ void k_spmf(const half8* __restrict__ Ah8, _Float16* __restrict__ outh,
                       const _Float16* __restrict__ Wh,
                       const float* __restrict__ bias, const float* __restrict__ g,
                       const float* __restrict__ be, const float* __restrict__ aP,
                       const float* __restrict__ dinv_in, const float* __restrict__ dinv_out,
                       const int* __restrict__ mflag,
                       const int* __restrict__ deg, const unsigned short* __restrict__ col) {
    __shared__ _Float16 shh[16][136];
    __shared__ float shc[16][132];
    __shared__ float smu[16], srs[16];
    int t = threadIdx.x;
    int w = t >> 6, lane = t & 63;
    int rl = lane & 15, quad4 = lane >> 4;
    int qid = w * 4 + quad4;
    int r0 = blockIdx.x * 16; // N % 16 == 0
    GATHERQ2(r0 + lr)
    __syncthreads();
    f32x4 c0 = {0.f, 0.f, 0.f, 0.f}, c1 = c0, c2 = c0, c3 = c0;
    MFMA_PHASE(Wh, c0, c1, c2, c3)
    STORE_SHC(c0, c1, c2, c3)
    __syncthreads();
    if constexpr (LN) {
        int row = t >> 3, seg = t & 7; // 8 threads/row, 16 cols each
        float di = dinv_in[r0 + row];
        float s = 0.f, qq = 0.f;
#pragma unroll
        for (int c = 0; c < 16; ++c) {
            int cc = seg * 16 + c;
            float v = (shc[row][cc] + bias[cc]) * di;
            s += v;
            qq += v * v;
        }
#pragma unroll
        for (int o = 1; o <= 4; o <<= 1) {
            s += __shfl_xor(s, o);
            qq += __shfl_xor(qq, o);
        }
        if (seg == 0) {
            float mu = s * (1.f / 128.f);
            float var = qq * (1.f / 128.f) - mu * mu;
            smu[row] = mu;
            srs[row] = rsqrtf(var + 1e-5f);
        }
        __syncthreads();
    }
    int lane64 = t & 63, grp = t >> 6;
    int cc0 = lane64 * 2, cc1 = cc0 + 1;
    float bt0 = 0.f, bt1 = 0.f, gt0 = 0.f, gt1 = 0.f, be0 = 0.f, be1 = 0.f, alpha = 0.f;
    if constexpr (LN) {
        bt0 = bias[cc0]; bt1 = bias[cc1];
        gt0 = g[cc0]; gt1 = g[cc1];
        be0 = be[cc0]; be1 = be[cc1];
        alpha = aP[0];
    }
#pragma unroll
    for (int i = 0; i < 8; ++i) {
        int lr = grp * 8 + i, r = r0 + lr;
        float v0 = shc[lr][cc0], v1 = shc[lr][cc1];
        if constexpr (LN) {
            float di = dinv_in[r];
            v0 = (v0 + bt0) * di;
            v1 = (v1 + bt1) * di;
            float mu = smu[lr], rs = srs[lr];
            v0 = (v0 - mu) * rs * gt0 + be0;
            v1 = (v1 - mu) * rs * gt1 + be1;
            v0 = v0 >= 0.f ? v0 : alpha * v0;
            v1 = v1 >= 0.f ? v1 : alpha * v1;
        }
        if (MASK_ZERO && mflag[r]) { v0 = 0.f; v1 = 0.f; }
        if constexpr (SCALE_OUT) {
            float so = dinv_out[r];
            v0 *= so; v1 *= so;
        }
        half2v hv;
        hv[0] = (_Float16)v0;
        hv[1] = (_Float16)v1;
        *(half2v*)(outh + (size_t)r * 128 + cc0) = hv;
    }
}

// ---------------- fused SpMM + conv2-fc/LN + encoder_to_decoder --------------

__launch_bounds__(128)
__global__ void k_spmf2(const half8* __restrict__ Ah8, _Float16* __restrict__ outh,
                        const _Float16* __restrict__ Wh2, const _Float16* __restrict__ WhE,
                        const float* __restrict__ bias, const float* __restrict__ g,
                        const float* __restrict__ be, const float* __restrict__ aP,
                        const float* __restrict__ dinv_in, const float* __restrict__ dinv_out,
                        const int* __restrict__ mflag,
                        const int* __restrict__ deg, const unsigned short* __restrict__ col) {
    __shared__ _Float16 shh[16][136];
    __shared__ float shc[16][132];
    __shared__ float smu[16], srs[16], sdo[16];
    __shared__ int smf[16];
    int t = threadIdx.x;
    int w = t >> 6, lane = t & 63;
    int rl = lane & 15, quad4 = lane >> 4;
    int qid = w * 4 + quad4;
    int r0 = blockIdx.x * 16;
    if (t < 16) {
        int r = r0 + t;
        sdo[t] = dinv_out[r];
        smf[t] = mflag[r];
    }
    GATHERQ2(r0 + lr)
    __syncthreads();
    f32x4 c0 = {0.f, 0.f, 0.f, 0.f}, c1 = c0, c2 = c0, c3 = c0;
    MFMA_PHASE(Wh2, c0, c1, c2, c3)
    STORE_SHC(c0, c1, c2, c3)
    __syncthreads();
    { // LN stats
        int row = t >> 3, seg = t & 7;
        float di = dinv_in[r0 + row];
        float s = 0.f, qq = 0.f;
#pragma unroll
        for (int c = 0; c < 16; ++c) {
            int cc = seg * 16 + c;
            float v = (shc[row][cc] + bias[cc]) * di;
            s += v;
            qq += v * v;
        }
#pragma unroll
        for (int o = 1; o <= 4; o <<= 1) {
            s += __shfl_xor(s, o);
            qq += __shfl_xor(qq, o);
        }
        if (seg == 0) {
            float mu = s * (1.f / 128.f);
            float var = qq * (1.f / 128.f) - mu * mu;
            smu[row] = mu;
            srs[row] = rsqrtf(var + 1e-5f);
        }
        __syncthreads();
    }
    { // h2 -> shh (fp16)
        int lane64 = t & 63, grp = t >> 6;
        int cc0 = lane64 * 2, cc1 = cc0 + 1;
        float bt0 = bias[cc0], bt1 = bias[cc1];
        float gt0 = g[cc0], gt1 = g[cc1];
        float be0 = be[cc0], be1 = be[cc1];
        float alpha = aP[0];
#pragma unroll
        for (int i = 0; i < 8; ++i) {
            int lr = grp * 8 + i, r = r0 + lr;
            float di = dinv_in[r];
            float v0 = (shc[lr][cc0] + bt0) * di;
            float v1 = (shc[lr][cc1] + bt1) * di;
            float mu = smu[lr], rs = srs[lr];
            v0 = (v0 - mu) * rs * gt0 + be0;
            v1 = (v1 - mu) * rs * gt1 + be1;
            v0 = v0 >= 0.f ? v0 : alpha * v0;
            v1 = v1 >= 0.f ? v1 : alpha * v1;
            shh[lr][cc0] = (_Float16)v0;
            shh[lr][cc1] = (_Float16)v1;
        }
    }
    __syncthreads();
    f32x4 d0 = {0.f, 0.f, 0.f, 0.f}, d1 = d0, d2 = d0, d3 = d0;
    MFMA_PHASE(WhE, d0, d1, d2, d3)
    // register-direct epilogue: re-mask + dinv_out scale
#pragma unroll
    for (int reg = 0; reg < 4; ++reg) {
        int lr = quad4 * 4 + reg, r = r0 + lr;
        float s = smf[lr] ? 0.f : sdo[lr];
        outh[(size_t)r * 128 + w * 64 + rl] = (_Float16)(d0[reg] * s);
        outh[(size_t)r * 128 + w * 64 + 16 + rl] = (_Float16)(d1[reg] * s);
        outh[(size_t)r * 128 + w * 64 + 32 + rl] = (_Float16)(d2[reg] * s);
        outh[(size_t)r * 128 + w * 64 + 48 + rl] = (_Float16)(d3[reg] * s);
    }
}

// ---------------- fused conv3-SpMM + decoder fc + SCE loss -------------------

__launch_bounds__(128)
__global__ void k_spmf_loss(const half8* __restrict__ Ah8, const float* __restrict__ x,
                            const _Float16* __restrict__ Wh, const float* __restrict__ bd,
                            const int* __restrict__ deg, const unsigned short* __restrict__ col,
                            const float* __restrict__ dinv_in,
                            const int* __restrict__ mask_nodes, float* __restrict__ outp) {
    __shared__ _Float16 shh[16][136];
    __shared__ float shc[16][132];
    __shared__ int shm[16];
    __shared__ float sterm[16];
    int t = threadIdx.x;
    int w = t >> 6, lane = t & 63;
    int rl = lane & 15, quad4 = lane >> 4;
    int qid = w * 4 + quad4;
    int i0 = blockIdx.x * 16;
    if (t < 16) {
        int idx = i0 + t;
        shm[t] = idx < MASKN ? mask_nodes[idx] : -1;
    }
    __syncthreads();
    GATHERQ2(shm[lr])
    __syncthreads();
    f32x4 c0 = {0.f, 0.f, 0.f, 0.f}, c1 = c0, c2 = c0, c3 = c0;
    MFMA_PHASE(Wh, c0, c1, c2, c3)
    STORE_SHC(c0, c1, c2, c3)
    __syncthreads();
    int row = t >> 3, seg = t & 7; // 8 threads/row, 16 cols each
    int m = shm[row];
    float a = 0.f, b = 0.f, c = 0.f;
    if (m >= 0) {
        float di = dinv_in[m];
#pragma unroll
        for (int cc0 = 0; cc0 < 16; ++cc0) {
            int cc = seg * 16 + cc0;
            float r = (shc[row][cc] + bd[cc]) * di;
            float xv = x[(size_t)m * 128 + cc];
            a += r * r;
            b += xv * xv;
            c += r * xv;
        }
    }
#pragma unroll
    for (int o = 1; o <= 4; o <<= 1) {
        a += __shfl_xor(a, o);
        b += __shfl_xor(b, o);
        c += __shfl_xor(c, o);
    }
    if (seg == 0) {
        float term = 0.f;
        if (m >= 0) {
            float nr = fmaxf(sqrtf(a), 1e-12f);
            float nx = fmaxf(sqrtf(b), 1e-12f);
            float d = 1.f - c / (nr * nx);
            term = d * d;
        }
        sterm[row] = term;
    }
    __syncthreads();
    if (t == 0) {
        float sum = 0.f;
#pragma unroll
        for (int i = 0; i < 16; ++i) sum += sterm[i];
        atomicAdd(outp, sum * (1.f / MASKN));
    }
}

// ---------------- launch ----------------

extern "C" void kernel_launch(void* const* d_in, const int* in_sizes, int n_in,
                              void* d_out, int out_size, void* d_ws, size_t ws_size,
                              hipStream_t stream) {
    const float* x = (const float*)d_in[0];
    const float* tok = (const float*)d_in[1];
    const float* W1 = (const float*)d_in[2];
    const float* b1 = (const float*)d_in[3];
    const float* g1 = (const float*)d_in[4];
    const float* be1 = (const float*)d_in[5];
    const float* a1 = (const float*)d_in[6];
    const float* W2 = (const float*)d_in[7];
    const float* b2 = (const float*)d_in[8];
    const float* g2 = (const float*)d_in[9];
    const float* be2 = (const float*)d_in[10];
    const float* a2 = (const float*)d_in[11];
    const float* We2d = (const float*)d_in[12];
    const float* Wd = (const float*)d_in[13];
    const float* bd = (const float*)d_in[14];
    const int* src = (const int*)d_in[15];
    const int* dst = (const int*)d_in[16];
    const int* mask_nodes = (const int*)d_in[17];

    char* w = (char*)d_ws;
    _Float16* Ah = (_Float16*)w;        w += (size_t)N * D * 2;
    _Float16* Bh = (_Float16*)w;        w += (size_t)N * D * 2;
    unsigned short* col = (unsigned short*)w; w += (size_t)N * CAP * 2;
    int* cursor = (int*)w;              w += (size_t)N * 4; // becomes deg_in
    int* mflag = (int*)w;               w += (size_t)N * 4;
    float* dinv_out = (float*)w;        w += (size_t)N * 4;
    float* dinv_in = (float*)w;         w += (size_t)N * 4;
    _Float16* Wh1 = (_Float16*)w;       w += (size_t)D * D * 2;
    _Float16* Wh2 = (_Float16*)w;       w += (size_t)D * D * 2;
    _Float16* WhE = (_Float16*)w;       w += (size_t)D * D * 2;
    _Float16* WhD = (_Float16*)w;       w += (size_t)D * D * 2;
    unsigned int* partial = (unsigned int*)w; w += (size_t)HB * HW * 4;

    // zero cursor, mflag (contiguous 2*N ints) + output scalar
    hipMemsetAsync(cursor, 0, (size_t)2 * N * 4, stream);
    hipMemsetAsync(d_out, 0, sizeof(float), stream);

    k_setup<<<NB_BUILD + NB_CAST + NB_MFLAG, 256, 0, stream>>>(
        src, dst, cursor, col, W1, W2, We2d, Wd, Wh1, Wh2, WhE, WhD,
        mask_nodes, mflag);
    k_hist<<<HB, 256, 0, stream>>>(src, partial);
    k_prep2<<<(N + 31) / 32, 256, 0, stream>>>(
        (const float4*)x, (const float4*)tok, partial, cursor, mflag,
        dinv_out, dinv_in, (half4*)Ah);
    int nmf = N / 16;               // 3125
    int nmfl = (MASKN + 15) / 16;   // 1563
    // conv1: agg + fc + LN + PReLU + pre-scale (fused) : Ah -> Bh
    k_spmf<true, true, false><<<nmf, 128, 0, stream>>>(
        (const half8*)Ah, Bh, Wh1, b1, g1, be1, a1, dinv_in, dinv_out, nullptr,
        cursor, col);
    // conv2: agg + fc/LN/PReLU + encoder_to_decoder + re-mask + pre-scale : Bh -> Ah
    k_spmf2<<<nmf, 128, 0, stream>>>(
        (const half8*)Bh, Ah, Wh2, WhE, b2, g2, be2, a2, dinv_in, dinv_out, mflag,
        cursor, col);
    // conv3 agg + decoder fc + SCE loss (fused)
    k_spmf_loss<<<nmfl, 128, 0, stream>>>((const half8*)Ah, x, WhD, bd, cursor, col,
                                          dinv_in, mask_nodes, (float*)d_out);
}